// Round 5
// baseline (1336.385 us; speedup 1.0000x reference)
//
#include <hip/hip_runtime.h>
#include <math.h>

typedef unsigned short u16;
typedef float f32x4 __attribute__((ext_vector_type(4)));
typedef __bf16 bf16x8 __attribute__((ext_vector_type(8)));
typedef short s16x8 __attribute__((ext_vector_type(8)));

__device__ __forceinline__ float bf2f(u16 u) {
    union { float f; unsigned int i; } v; v.i = ((unsigned int)u) << 16; return v.f;
}
__device__ __forceinline__ u16 f2bf(float f) {
    union { float f; unsigned int i; } v; v.f = f;
    unsigned int r = v.i + 0x7fffu + ((v.i >> 16) & 1u);
    return (u16)(r >> 16);
}

// 8-element row loaders -> bf16 (as s16x8). fp32 source converts during staging.
__device__ __forceinline__ s16x8 load8(const u16* p) { return *(const s16x8*)p; }
__device__ __forceinline__ s16x8 load8(const float* p) {
    f32x4 a = *(const f32x4*)p;
    f32x4 b = *(const f32x4*)(p + 4);
    s16x8 r;
    r[0] = (short)f2bf(a[0]); r[1] = (short)f2bf(a[1]);
    r[2] = (short)f2bf(a[2]); r[3] = (short)f2bf(a[3]);
    r[4] = (short)f2bf(b[0]); r[5] = (short)f2bf(b[1]);
    r[6] = (short)f2bf(b[2]); r[7] = (short)f2bf(b[3]);
    return r;
}

// ---------------- epilogue functors ----------------
struct EpiBF16 {            // bf16 store with batch stride
    u16* C; long zs; int ldc;
    __device__ void operator()(int z, int m, int n, float v) const {
        C[(long)z * zs + (long)m * ldc + n] = f2bf(v);
    }
};
struct EpiScale {           // scores: scale then bf16 store
    u16* C; long zs; int ldc; float s;
    __device__ void operator()(int z, int m, int n, float v) const {
        C[(long)z * zs + (long)m * ldc + n] = f2bf(v * s);
    }
};
struct EpiAcc {             // x2 += v  (fp32, 512-wide rows)
    float* x2;
    __device__ void operator()(int z, int m, int n, float v) const {
        x2[(long)m * 512 + n] += v;
    }
};
struct EpiBias16 {          // v + fp32 bias -> bf16
    u16* C; const float* bias;
    __device__ void operator()(int z, int m, int n, float v) const {
        C[(long)m * 512 + n] = f2bf(v + bias[n]);
    }
};

// ---------------- GEMM: C[m,n] = sum_k A[m,k] * B[n,k]  (bf16 compute, fp32 acc) --
// A: (M x K) bf16 rows lda.  B: (N x K) rows ldb, bf16 OR fp32 (converted in staging).
// Tile 64x64, BK=32. grid=(M/64, N/64, batch), block=256 (4 waves, 2x2 of 32x32).
#define LP 40   // padded LDS row stride (elements)
template <class BT, class Epi>
__launch_bounds__(256)
__global__ void gemm_bt(const u16* __restrict__ A, const BT* __restrict__ B,
                        int K, int lda, int ldb, long aBatch, long bBatch, Epi epi) {
    __shared__ __align__(16) u16 sA[64 * LP];
    __shared__ __align__(16) u16 sB[64 * LP];
    const int t = threadIdx.x;
    const int lane = t & 63, wave = t >> 6;
    const int wm = wave >> 1, wn = wave & 1;
    const int l15 = lane & 15, quad = lane >> 4;
    const int srow = t >> 2, schunk = (t & 3) * 8;
    const int m0 = blockIdx.x * 64, n0 = blockIdx.y * 64;
    const u16* Ab = A + (long)blockIdx.z * aBatch + (long)(m0 + srow) * lda + schunk;
    const BT*  Bb = B + (long)blockIdx.z * bBatch + (long)(n0 + srow) * ldb + schunk;
    f32x4 acc[2][2] = {};
    const int aoff = (wm * 32 + l15) * LP + quad * 8;
    const int boff = (wn * 32 + l15) * LP + quad * 8;
    for (int k0 = 0; k0 < K; k0 += 32) {
        s16x8 av = load8(Ab + k0);
        s16x8 bv = load8(Bb + k0);
        __syncthreads();
        *(s16x8*)(sA + srow * LP + schunk) = av;
        *(s16x8*)(sB + srow * LP + schunk) = bv;
        __syncthreads();
        bf16x8 a0 = *(const bf16x8*)(sA + aoff);
        bf16x8 a1 = *(const bf16x8*)(sA + aoff + 16 * LP);
        bf16x8 b0 = *(const bf16x8*)(sB + boff);
        bf16x8 b1 = *(const bf16x8*)(sB + boff + 16 * LP);
        acc[0][0] = __builtin_amdgcn_mfma_f32_16x16x32_bf16(a0, b0, acc[0][0], 0, 0, 0);
        acc[0][1] = __builtin_amdgcn_mfma_f32_16x16x32_bf16(a0, b1, acc[0][1], 0, 0, 0);
        acc[1][0] = __builtin_amdgcn_mfma_f32_16x16x32_bf16(a1, b0, acc[1][0], 0, 0, 0);
        acc[1][1] = __builtin_amdgcn_mfma_f32_16x16x32_bf16(a1, b1, acc[1][1], 0, 0, 0);
    }
    #pragma unroll
    for (int im = 0; im < 2; im++)
        #pragma unroll
        for (int in = 0; in < 2; in++)
            #pragma unroll
            for (int r = 0; r < 4; r++) {
                int m = m0 + wm * 32 + im * 16 + quad * 4 + r;   // C/D: row=(lane>>4)*4+reg
                int n = n0 + wn * 32 + in * 16 + l15;            //      col=lane&15
                epi(blockIdx.z, m, n, acc[im][in][r]);
            }
}

// ---------------- reductions / elementwise ----------------
__device__ __forceinline__ float waveSum(float v) {
    #pragma unroll
    for (int o = 32; o > 0; o >>= 1) v += __shfl_down(v, o, 64);
    return v;
}

__global__ void sumsq_f32(const float* __restrict__ x, float* __restrict__ part) {
    __shared__ float tmp[4];
    long base = (long)blockIdx.x * 524288 + (long)blockIdx.y * 8192;
    float s = 0.f;
    for (int i = threadIdx.x; i < 8192; i += 256) { float v = x[base + i]; s += v * v; }
    s = waveSum(s);
    if ((threadIdx.x & 63) == 0) tmp[threadIdx.x >> 6] = s;
    __syncthreads();
    if (threadIdx.x == 0) part[blockIdx.x * 64 + blockIdx.y] = tmp[0] + tmp[1] + tmp[2] + tmp[3];
}
__global__ void finalize_inv(const float* __restrict__ part, float* __restrict__ inv) {
    float s = part[blockIdx.x * 64 + threadIdx.x];
    s = waveSum(s);
    if (threadIdx.x == 0) inv[blockIdx.x] = sqrtf(524288.0f / s);  // 1/ff_rms
}
__global__ void rmsnorm1(const float* __restrict__ x, const float* __restrict__ scale,
                         const float* __restrict__ inv, u16* __restrict__ xnb) {
    long i = (long)blockIdx.x * 256 + threadIdx.x;
    int b = (int)(i >> 19), md = (int)(i & 524287);
    xnb[i] = f2bf(x[i] * inv[b] * scale[md]);
}
__global__ void init_x2(const float* __restrict__ x, const float* __restrict__ scale,
                        const float* __restrict__ inv, const float* __restrict__ bo,
                        float* __restrict__ x2) {
    long i = (long)blockIdx.x * 256 + threadIdx.x;
    int b = (int)(i >> 19), md = (int)(i & 524287);
    x2[i] = x[i] * inv[b] * scale[md] + bo[i & 511];   // xn (fp32) + bo
}
__global__ void rmsnorm2(const float* __restrict__ x2, const float* __restrict__ scale,
                         const float* __restrict__ inv, u16* __restrict__ x3b) {
    long i = (long)blockIdx.x * 256 + threadIdx.x;
    int b = (int)(i >> 19), md = (int)(i & 524287);
    x3b[i] = f2bf(x2[i] * inv[b] * scale[md]);
}
__global__ void rope_tables(float* __restrict__ cosT, float* __restrict__ sinT) {
    int i = blockIdx.x * 256 + threadIdx.x;      // 1024*256
    int m = i >> 8, j = i & 255;
    float theta = powf(10000.0f, -2.0f * ((float)j - 1.0f) / 512.0f);
    float ang = (float)m * theta;
    cosT[i] = cosf(ang); sinT[i] = sinf(ang);
}
__global__ void rope_apply(u16* __restrict__ tq, const float* __restrict__ cosT,
                           const float* __restrict__ sinT) {
    long i = (long)blockIdx.x * 256 + threadIdx.x;   // (b,m,256 pairs)
    int j = (int)(i & 255), m = (int)((i >> 8) & 1023);
    float c = cosT[m * 256 + j], s = sinT[m * 256 + j];
    long base = i * 2;
    float te = bf2f(tq[base]), to = bf2f(tq[base + 1]);
    tq[base]     = f2bf(te * c + to * s);
    tq[base + 1] = f2bf(-te * s + to * c);
}
__global__ void transpose_v(const u16* __restrict__ v, u16* __restrict__ vT) {
    __shared__ u16 tile[32][33];
    long zb = (long)blockIdx.z * 524288;            // per-batch (1024 x 512) slice
    int mo = blockIdx.x * 32, oo = blockIdx.y * 32;
    int tx = threadIdx.x & 31, ty = threadIdx.x >> 5;   // 32x8
    for (int r = ty; r < 32; r += 8) tile[r][tx] = v[zb + (long)(mo + r) * 512 + oo + tx];
    __syncthreads();
    for (int r = ty; r < 32; r += 8) vT[zb + (long)(oo + r) * 1024 + mo + tx] = tile[tx][r];
}
__launch_bounds__(256)
__global__ void softmax_rows(u16* __restrict__ sc) {
    __shared__ float tmp[4];
    u16* p = sc + (long)blockIdx.x * 1024;
    int t = threadIdx.x;
    float v[4]; float mx = -1e30f;
    #pragma unroll
    for (int i = 0; i < 4; i++) { v[i] = bf2f(p[t + 256 * i]); mx = fmaxf(mx, v[i]); }
    #pragma unroll
    for (int o = 32; o > 0; o >>= 1) mx = fmaxf(mx, __shfl_down(mx, o, 64));
    if ((t & 63) == 0) tmp[t >> 6] = mx;
    __syncthreads();
    mx = fmaxf(fmaxf(tmp[0], tmp[1]), fmaxf(tmp[2], tmp[3]));
    float sum = 0.f;
    #pragma unroll
    for (int i = 0; i < 4; i++) { v[i] = expf(v[i] - mx); sum += v[i]; }
    #pragma unroll
    for (int o = 32; o > 0; o >>= 1) sum += __shfl_down(sum, o, 64);
    __syncthreads();
    if ((t & 63) == 0) tmp[t >> 6] = sum;
    __syncthreads();
    sum = tmp[0] + tmp[1] + tmp[2] + tmp[3];
    float r = 1.0f / sum;
    #pragma unroll
    for (int i = 0; i < 4; i++) p[t + 256 * i] = f2bf(v[i] * r);
}
__global__ void final_out(const float* __restrict__ x2, const float* __restrict__ scale,
                          const float* __restrict__ inv2, const u16* __restrict__ g,
                          const u16* __restrict__ l, const float* __restrict__ beta,
                          float* __restrict__ out) {
    long i = (long)blockIdx.x * 256 + threadIdx.x;
    int b = (int)(i >> 19), md = (int)(i & 524287);
    float x3 = x2[i] * inv2[b] * scale[md];
    float gv = bf2f(g[i]), lv = bf2f(l[i]);
    float bta = beta[0];
    float sw = gv / (1.0f + expf(-bta * gv));   // g * sigmoid(beta*g)
    out[i] = x3 + sw * lv;                      // fp32 output
}

// ---------------- host ----------------
extern "C" void kernel_launch(void* const* d_in, const int* in_sizes, int n_in,
                              void* d_out, int out_size, void* d_ws, size_t ws_size,
                              hipStream_t stream) {
    (void)in_sizes; (void)n_in; (void)out_size;
    const float* x    = (const float*)d_in[0];
    const float* scale= (const float*)d_in[1];
    const float* Wq   = (const float*)d_in[2];
    const float* Wk   = (const float*)d_in[3];
    const float* Wv   = (const float*)d_in[4];
    const float* Wo   = (const float*)d_in[5];
    const float* bo   = (const float*)d_in[6];
    const float* Wff  = (const float*)d_in[7];
    const float* bff  = (const float*)d_in[8];
    const float* Wg   = (const float*)d_in[9];
    const float* bg   = (const float*)d_in[10];
    const float* Wl   = (const float*)d_in[11];
    const float* bl   = (const float*)d_in[12];
    const float* beta = (const float*)d_in[13];
    float* out = (float*)d_out;                  // fp32 output (reference dtype)

    char* ws = (char*)d_ws;
    // ---- workspace layout (peak 86.0 MB big path / 71.3 MB small path) ----
    u16*   xnb  = (u16*)  (ws + 0L);            //  8 MiB  bf16 xn (b,m,d)
    float* x2   = (float*)(ws + 8388608L);      // 16 MiB  fp32 x2 accum
    u16*   qh   = (u16*)  (ws + 25165824L);     //  8 MiB  per-head q (b,m,512)
    u16*   kh   = (u16*)  (ws + 33554432L);     //  8 MiB
    u16*   vh   = (u16*)  (ws + 41943040L);     //  8 MiB
    u16*   vT   = (u16*)  (ws + 50331648L);     //  8 MiB  (b,512,1024)
    u16*   ctx  = (u16*)  (ws + 58720256L);     //  8 MiB  (b,m,512)
    float* cosT = (float*)(ws + 67108864L);     //  1 MiB
    float* sinT = (float*)(ws + 68157440L);     //  1 MiB
    float* part = (float*)(ws + 69206016L);     //  2 KiB
    float* inv1 = (float*)(ws + 69208064L);
    float* inv2 = (float*)(ws + 69208128L);
    u16*   sc   = (u16*)  (ws + 69210112L);     // 16 MiB (big) / 2 MiB (small)
    // FF-phase reuse (attention per-head buffers are dead by then):
    u16*   x3b  = qh;
    u16*   h1   = kh;
    u16*   g    = vh;
    u16*   l    = vT;

    const bool bigSc = ws_size >= 85987328UL;    // room for 8-batch score chunk?
    const float sscale = 0.044194173824159216f;  // 1/sqrt(512)

    // 1) rmsnorm #1, rope tables, x2 init (x2 = xn_fp32 + bo)
    sumsq_f32<<<dim3(8, 64), 256, 0, stream>>>(x, part);
    finalize_inv<<<8, 64, 0, stream>>>(part, inv1);
    rmsnorm1<<<16384, 256, 0, stream>>>(x, scale, inv1, xnb);
    rope_tables<<<1024, 256, 0, stream>>>(cosT, sinT);
    init_x2<<<16384, 256, 0, stream>>>(x, scale, inv1, bo, x2);

    // 2) attention, one head at a time
    for (int h = 0; h < 8; h++) {
        const float* Wqh = Wq + (long)h * 262144;
        const float* Wkh = Wk + (long)h * 262144;
        const float* Wvh = Wv + (long)h * 262144;
        gemm_bt<<<dim3(128, 8, 1), 256, 0, stream>>>(xnb, Wqh, 512, 512, 512, 0L, 0L, EpiBF16{qh, 0L, 512});
        gemm_bt<<<dim3(128, 8, 1), 256, 0, stream>>>(xnb, Wkh, 512, 512, 512, 0L, 0L, EpiBF16{kh, 0L, 512});
        gemm_bt<<<dim3(128, 8, 1), 256, 0, stream>>>(xnb, Wvh, 512, 512, 512, 0L, 0L, EpiBF16{vh, 0L, 512});
        rope_apply<<<8192, 256, 0, stream>>>(qh, cosT, sinT);
        rope_apply<<<8192, 256, 0, stream>>>(kh, cosT, sinT);
        transpose_v<<<dim3(32, 16, 8), 256, 0, stream>>>(vh, vT);
        if (bigSc) {
            gemm_bt<<<dim3(16, 16, 8), 256, 0, stream>>>(qh, kh, 512, 512, 512, 524288L, 524288L,
                                                         EpiScale{sc, 1048576L, 1024, sscale});
            softmax_rows<<<8192, 256, 0, stream>>>(sc);
            gemm_bt<<<dim3(16, 8, 8), 256, 0, stream>>>(sc, vT, 1024, 1024, 1024, 1048576L, 524288L,
                                                        EpiBF16{ctx, 524288L, 512});
        } else {
            for (int b = 0; b < 8; b++) {
                gemm_bt<<<dim3(16, 16, 1), 256, 0, stream>>>(qh + (long)b * 524288, kh + (long)b * 524288,
                                                             512, 512, 512, 0L, 0L,
                                                             EpiScale{sc, 0L, 1024, sscale});
                softmax_rows<<<1024, 256, 0, stream>>>(sc);
                gemm_bt<<<dim3(16, 8, 1), 256, 0, stream>>>(sc, vT + (long)b * 524288, 1024, 1024, 1024,
                                                            0L, 0L, EpiBF16{ctx + (long)b * 524288, 0L, 512});
            }
        }
        // x2 += ctx @ Wo[:, h*512:(h+1)*512]^T
        gemm_bt<<<dim3(128, 8, 1), 256, 0, stream>>>(ctx, Wo + (long)h * 512, 512, 512, 4096, 0L, 0L,
                                                     EpiAcc{x2});
    }

    // 3) rmsnorm #2
    sumsq_f32<<<dim3(8, 64), 256, 0, stream>>>(x2, part);
    finalize_inv<<<8, 64, 0, stream>>>(part, inv2);
    rmsnorm2<<<16384, 256, 0, stream>>>(x2, scale, inv2, x3b);

    // 4) FF: h1 = x3@Wff^T+bff ; g = h1@Wg^T+bg ; l = h1@Wl^T+bl
    gemm_bt<<<dim3(128, 8, 1), 256, 0, stream>>>(x3b, Wff, 512, 512, 512, 0L, 0L, EpiBias16{h1, bff});
    gemm_bt<<<dim3(128, 8, 1), 256, 0, stream>>>(h1, Wg, 512, 512, 512, 0L, 0L, EpiBias16{g, bg});
    gemm_bt<<<dim3(128, 8, 1), 256, 0, stream>>>(h1, Wl, 512, 512, 512, 0L, 0L, EpiBias16{l, bl});

    // 5) out = x3 + (g*sigmoid(beta*g)) * l    (fp32 store)
    final_out<<<16384, 256, 0, stream>>>(x2, scale, inv2, g, l, beta, out);
}

// Round 6
// 1191.234 us; speedup vs baseline: 1.1218x; 1.1218x over previous
//
#include <hip/hip_runtime.h>
#include <math.h>

typedef unsigned short u16;
typedef float f32x4 __attribute__((ext_vector_type(4)));
typedef __bf16 bf16x8 __attribute__((ext_vector_type(8)));

__device__ __forceinline__ float bf2f(u16 u) {
    union { float f; unsigned int i; } v; v.i = ((unsigned int)u) << 16; return v.f;
}
__device__ __forceinline__ u16 f2bf(float f) {
    union { float f; unsigned int i; } v; v.f = f;
    unsigned int r = v.i + 0x7fffu + ((v.i >> 16) & 1u);
    return (u16)(r >> 16);
}

// async global->LDS, 16B per lane. LDS dest is wave-uniform base + lane*16.
__device__ __forceinline__ void gll(const u16* g, u16* l) {
    __builtin_amdgcn_global_load_lds((const __attribute__((address_space(1))) void*)g,
                                     (__attribute__((address_space(3))) void*)l, 16, 0, 0);
}

// ---------------- epilogue functors ----------------
struct EpiBF16 {            // bf16 store with batch stride
    u16* C; long zs; int ldc;
    __device__ void operator()(int z, int m, int n, float v) const {
        C[(long)z * zs + (long)m * ldc + n] = f2bf(v);
    }
};
struct EpiScale {           // scores: scale then bf16 store
    u16* C; long zs; int ldc; float s;
    __device__ void operator()(int z, int m, int n, float v) const {
        C[(long)z * zs + (long)m * ldc + n] = f2bf(v * s);
    }
};
struct EpiAcc {             // x2 += v  (fp32, 512-wide rows)
    float* x2;
    __device__ void operator()(int z, int m, int n, float v) const {
        x2[(long)m * 512 + n] += v;
    }
};
struct EpiBias16 {          // v + fp32 bias -> bf16
    u16* C; const float* bias;
    __device__ void operator()(int z, int m, int n, float v) const {
        C[(long)m * 512 + n] = f2bf(v + bias[n]);
    }
};

// ------- GEMM 128x128 tile, BK=32: C[m,n] = sum_k A[m,k]*B[n,k], bf16 in fp32 acc.
// m97 structure: global_load_lds(16B) staging, unpadded LDS + XOR column swizzle,
// 4 waves (2x2), each wave 4x4 frags of 16x16x32. M,N mult of 128, K mult of 32.
template <class Epi>
__launch_bounds__(256)
__global__ void gemm128(const u16* __restrict__ A, const u16* __restrict__ B,
                        int K, int lda, int ldb, long aBatch, long bBatch, Epi epi) {
    __shared__ __align__(16) u16 sA[4096];   // 128 x 32
    __shared__ __align__(16) u16 sB[4096];
    const int t = threadIdx.x;
    const int lane = t & 63, wave = t >> 6;
    const int wr = wave >> 1, wc = wave & 1;
    const int l15 = lane & 15, quad = lane >> 4;
    const int m0 = blockIdx.x * 128, n0 = blockIdx.y * 128;
    // staging: thread t covers LDS slot (row=t>>2, chunk=t&3); global column is
    // XOR-swizzled so frag reads are ~conflict-free while LDS stays lane-contiguous.
    const int sr = t >> 2;
    const int scw = ((t & 3) ^ ((t >> 3) & 3)) * 8;
    const u16* gA = A + (long)blockIdx.z * aBatch + (long)(m0 + sr) * lda + scw;
    const u16* gB = B + (long)blockIdx.z * bBatch + (long)(n0 + sr) * ldb + scw;
    const long a2 = 64L * lda, b2 = 64L * ldb;
    u16* lA = sA + wave * 512 + lane * 8;    // lane*16B within wave's 1KB slab
    u16* lB = sB + wave * 512 + lane * 8;
    // frag read offsets (swizzle-aware): A[row][quad*8..] at phys chunk quad^((row>>1)&3)
    const int ap = (quad ^ ((l15 >> 1) & 3)) * 8;
    const int ab = (wr * 64 + l15) * 32 + ap;
    const int bb = (wc * 64 + l15) * 32 + ap;
    f32x4 acc[4][4] = {};
    for (int k0 = 0; k0 < K; k0 += 32) {
        gll(gA + k0, lA); gll(gA + k0 + a2, lA + 2048);
        gll(gB + k0, lB); gll(gB + k0 + b2, lB + 2048);
        __syncthreads();                      // drains vmcnt -> LDS visible
        bf16x8 aF[4], bF[4];
        #pragma unroll
        for (int i = 0; i < 4; i++) aF[i] = *(const bf16x8*)(sA + ab + i * 512);
        #pragma unroll
        for (int j = 0; j < 4; j++) bF[j] = *(const bf16x8*)(sB + bb + j * 512);
        #pragma unroll
        for (int i = 0; i < 4; i++)
            #pragma unroll
            for (int j = 0; j < 4; j++)
                acc[i][j] = __builtin_amdgcn_mfma_f32_16x16x32_bf16(aF[i], bF[j], acc[i][j], 0, 0, 0);
        __syncthreads();                      // reads done before next overwrite
    }
    #pragma unroll
    for (int i = 0; i < 4; i++)
        #pragma unroll
        for (int j = 0; j < 4; j++)
            #pragma unroll
            for (int r = 0; r < 4; r++)
                epi(blockIdx.z, m0 + wr * 64 + i * 16 + quad * 4 + r,   // row=(lane>>4)*4+reg
                    n0 + wc * 64 + j * 16 + l15, acc[i][j][r]);         // col=lane&15
}

// ---------------- reductions / elementwise ----------------
__device__ __forceinline__ float waveSum(float v) {
    #pragma unroll
    for (int o = 32; o > 0; o >>= 1) v += __shfl_down(v, o, 64);
    return v;
}

__global__ void sumsq_f32(const float* __restrict__ x, float* __restrict__ part) {
    __shared__ float tmp[4];
    long base = (long)blockIdx.x * 524288 + (long)blockIdx.y * 8192;
    float s = 0.f;
    for (int i = threadIdx.x; i < 8192; i += 256) { float v = x[base + i]; s += v * v; }
    s = waveSum(s);
    if ((threadIdx.x & 63) == 0) tmp[threadIdx.x >> 6] = s;
    __syncthreads();
    if (threadIdx.x == 0) part[blockIdx.x * 64 + blockIdx.y] = tmp[0] + tmp[1] + tmp[2] + tmp[3];
}
__global__ void finalize_inv(const float* __restrict__ part, float* __restrict__ inv) {
    float s = part[blockIdx.x * 64 + threadIdx.x];
    s = waveSum(s);
    if (threadIdx.x == 0) inv[blockIdx.x] = sqrtf(524288.0f / s);  // 1/ff_rms
}
__global__ void rmsnorm1f(const float* __restrict__ x, const float* __restrict__ scale,
                          const float* __restrict__ inv, const float* __restrict__ bo,
                          u16* __restrict__ xnb, float* __restrict__ x2) {
    long i = (long)blockIdx.x * 256 + threadIdx.x;
    int b = (int)(i >> 19), md = (int)(i & 524287);
    float v = x[i] * inv[b] * scale[md];
    xnb[i] = f2bf(v);
    x2[i] = v + bo[i & 511];
}
__global__ void rmsnorm2(const float* __restrict__ x2, const float* __restrict__ scale,
                         const float* __restrict__ inv, u16* __restrict__ x3b) {
    long i = (long)blockIdx.x * 256 + threadIdx.x;
    int b = (int)(i >> 19), md = (int)(i & 524287);
    x3b[i] = f2bf(x2[i] * inv[b] * scale[md]);
}
__global__ void rope_tables(float* __restrict__ cosT, float* __restrict__ sinT) {
    int i = blockIdx.x * 256 + threadIdx.x;      // 1024*256
    int m = i >> 8, j = i & 255;
    float theta = powf(10000.0f, -2.0f * ((float)j - 1.0f) / 512.0f);
    float ang = (float)m * theta;
    cosT[i] = cosf(ang); sinT[i] = sinf(ang);
}
__global__ void rope_apply(u16* __restrict__ tq, const float* __restrict__ cosT,
                           const float* __restrict__ sinT) {
    long i = (long)blockIdx.x * 256 + threadIdx.x;   // pairs over contiguous (q|k)
    int j = (int)(i & 255), m = (int)((i >> 8) & 1023);
    float c = cosT[m * 256 + j], s = sinT[m * 256 + j];
    long base = i * 2;
    float te = bf2f(tq[base]), to = bf2f(tq[base + 1]);
    tq[base]     = f2bf(te * c + to * s);
    tq[base + 1] = f2bf(-te * s + to * c);
}
__global__ void transpose_v(const u16* __restrict__ v, u16* __restrict__ vT) {
    __shared__ u16 tile[32][33];
    long zb = (long)blockIdx.z * 524288;            // per-batch (1024 x 512) slice
    int mo = blockIdx.x * 32, oo = blockIdx.y * 32;
    int tx = threadIdx.x & 31, ty = threadIdx.x >> 5;   // 32x8
    for (int r = ty; r < 32; r += 8) tile[r][tx] = v[zb + (long)(mo + r) * 512 + oo + tx];
    __syncthreads();
    for (int r = ty; r < 32; r += 8) vT[zb + (long)(oo + r) * 1024 + mo + tx] = tile[tx][r];
}
__launch_bounds__(256)
__global__ void softmax_rows(u16* __restrict__ sc) {
    __shared__ float tmp[4];
    u16* p = sc + (long)blockIdx.x * 1024;
    int t = threadIdx.x;
    float v[4]; float mx = -1e30f;
    #pragma unroll
    for (int i = 0; i < 4; i++) { v[i] = bf2f(p[t + 256 * i]); mx = fmaxf(mx, v[i]); }
    #pragma unroll
    for (int o = 32; o > 0; o >>= 1) mx = fmaxf(mx, __shfl_down(mx, o, 64));
    if ((t & 63) == 0) tmp[t >> 6] = mx;
    __syncthreads();
    mx = fmaxf(fmaxf(tmp[0], tmp[1]), fmaxf(tmp[2], tmp[3]));
    float sum = 0.f;
    #pragma unroll
    for (int i = 0; i < 4; i++) { v[i] = expf(v[i] - mx); sum += v[i]; }
    #pragma unroll
    for (int o = 32; o > 0; o >>= 1) sum += __shfl_down(sum, o, 64);
    __syncthreads();
    if ((t & 63) == 0) tmp[t >> 6] = sum;
    __syncthreads();
    sum = tmp[0] + tmp[1] + tmp[2] + tmp[3];
    float r = 1.0f / sum;
    #pragma unroll
    for (int i = 0; i < 4; i++) p[t + 256 * i] = f2bf(v[i] * r);
}
__global__ void final_out(const float* __restrict__ x2, const float* __restrict__ scale,
                          const float* __restrict__ inv2, const u16* __restrict__ g,
                          const u16* __restrict__ l, const float* __restrict__ beta,
                          float* __restrict__ out) {
    long i = (long)blockIdx.x * 256 + threadIdx.x;
    int b = (int)(i >> 19), md = (int)(i & 524287);
    float x3 = x2[i] * inv2[b] * scale[md];
    float gv = bf2f(g[i]), lv = bf2f(l[i]);
    float bta = beta[0];
    float sw = gv / (1.0f + expf(-bta * gv));   // g * sigmoid(beta*g)
    out[i] = x3 + sw * lv;                      // fp32 output
}
__global__ void convert_f2b(const float* __restrict__ s, u16* __restrict__ d, int n) {
    int i = blockIdx.x * 256 + threadIdx.x;
    if (i < n) d[i] = f2bf(s[i]);
}
__global__ void convert3(const float* __restrict__ a, const float* __restrict__ b,
                         const float* __restrict__ c, u16* __restrict__ d) {
    int i = blockIdx.x * 256 + threadIdx.x;      // [0, 786432)
    const float* s = (i < 262144) ? a : (i < 524288) ? b : c;
    d[i] = f2bf(s[i & 262143]);
}

// ---------------- host ----------------
extern "C" void kernel_launch(void* const* d_in, const int* in_sizes, int n_in,
                              void* d_out, int out_size, void* d_ws, size_t ws_size,
                              hipStream_t stream) {
    (void)in_sizes; (void)n_in; (void)out_size;
    const float* x    = (const float*)d_in[0];
    const float* scale= (const float*)d_in[1];
    const float* Wq   = (const float*)d_in[2];
    const float* Wk   = (const float*)d_in[3];
    const float* Wv   = (const float*)d_in[4];
    const float* Wo   = (const float*)d_in[5];
    const float* bo   = (const float*)d_in[6];
    const float* Wff  = (const float*)d_in[7];
    const float* bff  = (const float*)d_in[8];
    const float* Wg   = (const float*)d_in[9];
    const float* bg   = (const float*)d_in[10];
    const float* Wl   = (const float*)d_in[11];
    const float* bl   = (const float*)d_in[12];
    const float* beta = (const float*)d_in[13];
    float* out = (float*)d_out;                  // fp32 output

    char* ws = (char*)d_ws;
    // ---- workspace layout (big path 84.9 MB, small path 70.2 MB) ----
    u16*   xnb  = (u16*)  (ws + 0L);             //  8 MiB  bf16 xn
    float* x2   = (float*)(ws + 8388608L);       // 16 MiB  fp32 x2 accum
    u16*   qh   = (u16*)  (ws + 25165824L);      //  8 MiB  per-head q   (b,m,512)
    u16*   kh   = (u16*)  (ws + 33554432L);      //  8 MiB  per-head k   (contiguous after qh!)
    u16*   vhc  = (u16*)  (ws + 41943040L);      //  8 MiB  v, then ctx
    u16*   vT   = (u16*)  (ws + 50331648L);      //  8 MiB  (b,512,1024)
    u16*   Whb  = (u16*)  (ws + 58720256L);      //  1.5 MiB [Wq|Wk|Wv] head slice bf16
    u16*   Wob  = (u16*)  (ws + 60293120L);      //  4 MiB
    u16*   Wfb  = (u16*)  (ws + 64487424L);      //  0.5 MiB
    u16*   Wgb  = (u16*)  (ws + 65011712L);      //  0.5 MiB
    u16*   Wlb  = (u16*)  (ws + 65536000L);      //  0.5 MiB
    float* cosT = (float*)(ws + 66060288L);      //  1 MiB
    float* sinT = (float*)(ws + 67108864L);      //  1 MiB
    float* part = (float*)(ws + 68157440L);      //  2 KiB
    float* inv1 = (float*)(ws + 68159488L);
    float* inv2 = (float*)(ws + 68159552L);
    u16*   sc   = (u16*)  (ws + 68159616L);      // 16 MiB (big) / 2 MiB (small)
    // FF-phase reuse:
    u16*   x3b = qh;  u16* h1 = kh;  u16* g = vhc;  u16* l = vT;

    const bool big = ws_size >= 84936832UL + 65536UL;   // sc end + slack
    const float sscale = 0.044194173824159216f;          // 1/sqrt(512)

    // 1) rmsnorm #1 (+ x2 = xn + bo), rope tables, weight conversions
    sumsq_f32<<<dim3(8, 64), 256, 0, stream>>>(x, part);
    finalize_inv<<<8, 64, 0, stream>>>(part, inv1);
    rmsnorm1f<<<16384, 256, 0, stream>>>(x, scale, inv1, bo, xnb, x2);
    rope_tables<<<1024, 256, 0, stream>>>(cosT, sinT);
    convert_f2b<<<8192, 256, 0, stream>>>(Wo, Wob, 2097152);
    convert_f2b<<<1024, 256, 0, stream>>>(Wff, Wfb, 262144);
    convert_f2b<<<1024, 256, 0, stream>>>(Wg, Wgb, 262144);
    convert_f2b<<<1024, 256, 0, stream>>>(Wl, Wlb, 262144);

    // 2) attention, one head at a time
    for (int h = 0; h < 8; h++) {
        convert3<<<3072, 256, 0, stream>>>(Wq + (long)h * 262144, Wk + (long)h * 262144,
                                           Wv + (long)h * 262144, Whb);
        // q|k|v = xn @ {Wq,Wk,Wv}[h]^T   (z indexes the three)
        gemm128<<<dim3(64, 4, 3), 256, 0, stream>>>(xnb, Whb, 512, 512, 512, 0L, 262144L,
                                                    EpiBF16{qh, 4194304L, 512});
        rope_apply<<<32768, 256, 0, stream>>>(qh, cosT, sinT);   // q and k (contiguous)
        transpose_v<<<dim3(32, 16, 8), 256, 0, stream>>>(vhc, vT);
        if (big) {
            gemm128<<<dim3(8, 8, 8), 256, 0, stream>>>(qh, kh, 512, 512, 512, 524288L, 524288L,
                                                       EpiScale{sc, 1048576L, 1024, sscale});
            softmax_rows<<<8192, 256, 0, stream>>>(sc);
            gemm128<<<dim3(8, 4, 8), 256, 0, stream>>>(sc, vT, 1024, 1024, 1024, 1048576L, 524288L,
                                                       EpiBF16{vhc, 524288L, 512});
        } else {
            for (int b = 0; b < 8; b++) {
                gemm128<<<dim3(8, 8, 1), 256, 0, stream>>>(qh + (long)b * 524288, kh + (long)b * 524288,
                                                           512, 512, 512, 0L, 0L,
                                                           EpiScale{sc, 0L, 1024, sscale});
                softmax_rows<<<1024, 256, 0, stream>>>(sc);
                gemm128<<<dim3(8, 4, 1), 256, 0, stream>>>(sc, vT + (long)b * 524288, 1024, 1024, 1024,
                                                           0L, 0L, EpiBF16{vhc + (long)b * 524288, 0L, 512});
            }
        }
        // x2 += ctx @ Wo[:, h*512:(h+1)*512]^T
        gemm128<<<dim3(64, 4, 1), 256, 0, stream>>>(vhc, Wob + (long)h * 512, 512, 512, 4096, 0L, 0L,
                                                    EpiAcc{x2});
    }

    // 3) rmsnorm #2
    sumsq_f32<<<dim3(8, 64), 256, 0, stream>>>(x2, part);
    finalize_inv<<<8, 64, 0, stream>>>(part, inv2);
    rmsnorm2<<<16384, 256, 0, stream>>>(x2, scale, inv2, x3b);

    // 4) FF: h1 = x3@Wff^T+bff ; g = h1@Wg^T+bg ; l = h1@Wl^T+bl
    gemm128<<<dim3(64, 4, 1), 256, 0, stream>>>(x3b, Wfb, 512, 512, 512, 0L, 0L, EpiBias16{h1, bff});
    gemm128<<<dim3(64, 4, 1), 256, 0, stream>>>(h1, Wgb, 512, 512, 512, 0L, 0L, EpiBias16{g, bg});
    gemm128<<<dim3(64, 4, 1), 256, 0, stream>>>(h1, Wlb, 512, 512, 512, 0L, 0L, EpiBias16{l, bl});

    // 5) out = x3 + (g*sigmoid(beta*g)) * l    (fp32 store)
    final_out<<<16384, 256, 0, stream>>>(x2, scale, inv2, g, l, beta, out);
}

// Round 7
// 921.406 us; speedup vs baseline: 1.4504x; 1.2928x over previous
//
#include <hip/hip_runtime.h>
#include <math.h>

typedef unsigned short u16;
typedef float f32x4 __attribute__((ext_vector_type(4)));
typedef __bf16 bf16x8 __attribute__((ext_vector_type(8)));

__device__ __forceinline__ float bf2f(u16 u) {
    union { float f; unsigned int i; } v; v.i = ((unsigned int)u) << 16; return v.f;
}
__device__ __forceinline__ u16 f2bf(float f) {
    union { float f; unsigned int i; } v; v.f = f;
    unsigned int r = v.i + 0x7fffu + ((v.i >> 16) & 1u);
    return (u16)(r >> 16);
}

// async global->LDS, 16B per lane. LDS dest is wave-uniform base + lane*16.
__device__ __forceinline__ void gll(const u16* g, u16* l) {
    __builtin_amdgcn_global_load_lds((const __attribute__((address_space(1))) void*)g,
                                     (__attribute__((address_space(3))) void*)l, 16, 0, 0);
}

// ---------------- epilogue functors ----------------
struct EpiBF16 {            // bf16 store with batch stride
    u16* C; long zs; int ldc;
    __device__ void operator()(int z, int m, int n, float v) const {
        C[(long)z * zs + (long)m * ldc + n] = f2bf(v);
    }
};
struct EpiScale {           // scores: scale then bf16 store
    u16* C; long zs; int ldc; float s;
    __device__ void operator()(int z, int m, int n, float v) const {
        C[(long)z * zs + (long)m * ldc + n] = f2bf(v * s);
    }
};
struct EpiAcc {             // x2 += v  (fp32, 512-wide rows)
    float* x2;
    __device__ void operator()(int z, int m, int n, float v) const {
        x2[(long)m * 512 + n] += v;
    }
};
struct EpiBias16 {          // v + fp32 bias -> bf16
    u16* C; const float* bias;
    __device__ void operator()(int z, int m, int n, float v) const {
        C[(long)m * 512 + n] = f2bf(v + bias[n]);
    }
};
struct EpiGL {              // split N=1024 into g (n<512) and l, with biases
    u16* g; u16* l; const float* bg; const float* bl;
    __device__ void operator()(int z, int m, int n, float v) const {
        if (n < 512) g[(long)m * 512 + n] = f2bf(v + bg[n]);
        else         l[(long)m * 512 + n - 512] = f2bf(v + bl[n - 512]);
    }
};
struct EpiQKV {             // z = which*8+h; rope q/k in-register; v stored transposed
    u16* q; u16* k; u16* vT; const float* cosT; const float* sinT;
    __device__ void operator()(int z, int m, int n, float v) const {
        int which = z >> 3, h = z & 7;
        long hb = (long)h * 4194304;
        if (which < 2) {
            float p = __shfl_xor(v, 1, 64);        // partner col (adjacent lane)
            int j = (n >> 1) & 255, mr = m & 1023;
            float c = cosT[mr * 256 + j], s = sinT[mr * 256 + j];
            float te = (n & 1) ? p : v, to = (n & 1) ? v : p;
            v = (n & 1) ? (-te * s + to * c) : (te * c + to * s);
            u16* dst = which ? k : q;
            dst[hb + (long)m * 512 + n] = f2bf(v);
        } else {
            vT[hb + (long)(m >> 10) * 524288 + (long)n * 1024 + (m & 1023)] = f2bf(v);
        }
    }
};

// ------- GEMM 128x128 tile, BK=32: C[m,n] = sum_{s,k} A[m, s,k]*B[n, s*Kseg+k].
// m97 structure: global_load_lds(16B), unpadded LDS + XOR column swizzle, 4 waves,
// each wave 4x4 frags of 16x16x32. Segmented K: nSeg segments of Kseg; A advances
// by aSeg elems per segment, B's row is contiguous nSeg*Kseg wide.
template <class Epi>
__launch_bounds__(256)
__global__ void gemm128(const u16* __restrict__ A, const u16* __restrict__ B,
                        int Kseg, int nSeg, int lda, int ldb,
                        long aBatch, long bBatch, long aSeg, Epi epi) {
    __shared__ __align__(16) u16 sA[4096];   // 128 x 32
    __shared__ __align__(16) u16 sB[4096];
    const int t = threadIdx.x;
    const int lane = t & 63, wave = t >> 6;
    const int wr = wave >> 1, wc = wave & 1;
    const int l15 = lane & 15, quad = lane >> 4;
    const int m0 = blockIdx.x * 128, n0 = blockIdx.y * 128;
    const int sr = t >> 2;
    const int scw = ((t & 3) ^ ((t >> 3) & 3)) * 8;
    const u16* gA = A + (long)blockIdx.z * aBatch + (long)(m0 + sr) * lda + scw;
    const u16* gB = B + (long)blockIdx.z * bBatch + (long)(n0 + sr) * ldb + scw;
    const long a2 = 64L * lda, b2 = 64L * ldb;
    u16* lA = sA + wave * 512 + lane * 8;
    u16* lB = sB + wave * 512 + lane * 8;
    const int ap = (quad ^ ((l15 >> 1) & 3)) * 8;
    const int ab = (wr * 64 + l15) * 32 + ap;
    const int bb = (wc * 64 + l15) * 32 + ap;
    f32x4 acc[4][4] = {};
    for (int s = 0; s < nSeg; s++) {
        const u16* gAs = gA + (long)s * aSeg;
        const u16* gBs = gB + s * Kseg;
        for (int k0 = 0; k0 < Kseg; k0 += 32) {
            gll(gAs + k0, lA); gll(gAs + k0 + a2, lA + 2048);
            gll(gBs + k0, lB); gll(gBs + k0 + b2, lB + 2048);
            __syncthreads();
            bf16x8 aF[4], bF[4];
            #pragma unroll
            for (int i = 0; i < 4; i++) aF[i] = *(const bf16x8*)(sA + ab + i * 512);
            #pragma unroll
            for (int j = 0; j < 4; j++) bF[j] = *(const bf16x8*)(sB + bb + j * 512);
            #pragma unroll
            for (int i = 0; i < 4; i++)
                #pragma unroll
                for (int j = 0; j < 4; j++)
                    acc[i][j] = __builtin_amdgcn_mfma_f32_16x16x32_bf16(aF[i], bF[j], acc[i][j], 0, 0, 0);
            __syncthreads();
        }
    }
    #pragma unroll
    for (int i = 0; i < 4; i++)
        #pragma unroll
        for (int j = 0; j < 4; j++)
            #pragma unroll
            for (int r = 0; r < 4; r++)
                epi(blockIdx.z, m0 + wr * 64 + i * 16 + quad * 4 + r,   // row=(lane>>4)*4+reg
                    n0 + wc * 64 + j * 16 + l15, acc[i][j][r]);         // col=lane&15
}

// ---------------- reductions / elementwise ----------------
__device__ __forceinline__ float waveSum(float v) {
    #pragma unroll
    for (int o = 32; o > 0; o >>= 1) v += __shfl_down(v, o, 64);
    return v;
}

__global__ void sumsq_f32(const float* __restrict__ x, float* __restrict__ part) {
    __shared__ float tmp[4];
    long base = (long)blockIdx.x * 524288 + (long)blockIdx.y * 8192;
    float s = 0.f;
    for (int i = threadIdx.x; i < 8192; i += 256) { float v = x[base + i]; s += v * v; }
    s = waveSum(s);
    if ((threadIdx.x & 63) == 0) tmp[threadIdx.x >> 6] = s;
    __syncthreads();
    if (threadIdx.x == 0) part[blockIdx.x * 64 + blockIdx.y] = tmp[0] + tmp[1] + tmp[2] + tmp[3];
}
__global__ void finalize_inv(const float* __restrict__ part, float* __restrict__ inv) {
    float s = part[blockIdx.x * 64 + threadIdx.x];
    s = waveSum(s);
    if (threadIdx.x == 0) inv[blockIdx.x] = sqrtf(524288.0f / s);  // 1/ff_rms
}
__global__ void rmsnorm1f(const float* __restrict__ x, const float* __restrict__ scale,
                          const float* __restrict__ inv, const float* __restrict__ bo,
                          u16* __restrict__ xnb, float* __restrict__ x2) {
    long i = (long)blockIdx.x * 256 + threadIdx.x;
    int b = (int)(i >> 19), md = (int)(i & 524287);
    float v = x[i] * inv[b] * scale[md];
    xnb[i] = f2bf(v);
    x2[i] = v + bo[i & 511];
}
__global__ void rmsnorm2(const float* __restrict__ x2, const float* __restrict__ scale,
                         const float* __restrict__ inv, u16* __restrict__ x3b) {
    long i = (long)blockIdx.x * 256 + threadIdx.x;
    int b = (int)(i >> 19), md = (int)(i & 524287);
    x3b[i] = f2bf(x2[i] * inv[b] * scale[md]);
}
__global__ void rope_tables(float* __restrict__ cosT, float* __restrict__ sinT) {
    int i = blockIdx.x * 256 + threadIdx.x;      // 1024*256
    int m = i >> 8, j = i & 255;
    float theta = powf(10000.0f, -2.0f * ((float)j - 1.0f) / 512.0f);
    float ang = (float)m * theta;
    cosT[i] = cosf(ang); sinT[i] = sinf(ang);
}
__global__ void rope_apply(u16* __restrict__ tq, const float* __restrict__ cosT,
                           const float* __restrict__ sinT) {
    long i = (long)blockIdx.x * 256 + threadIdx.x;
    int j = (int)(i & 255), m = (int)((i >> 8) & 1023);
    float c = cosT[m * 256 + j], s = sinT[m * 256 + j];
    long base = i * 2;
    float te = bf2f(tq[base]), to = bf2f(tq[base + 1]);
    tq[base]     = f2bf(te * c + to * s);
    tq[base + 1] = f2bf(-te * s + to * c);
}
__global__ void transpose_v(const u16* __restrict__ v, u16* __restrict__ vT) {
    __shared__ u16 tile[32][33];
    long zb = (long)blockIdx.z * 524288;
    int mo = blockIdx.x * 32, oo = blockIdx.y * 32;
    int tx = threadIdx.x & 31, ty = threadIdx.x >> 5;
    for (int r = ty; r < 32; r += 8) tile[r][tx] = v[zb + (long)(mo + r) * 512 + oo + tx];
    __syncthreads();
    for (int r = ty; r < 32; r += 8) vT[zb + (long)(oo + r) * 1024 + mo + tx] = tile[tx][r];
}
// wave-per-row softmax: grid = rows/4, block 256 (4 waves), no barriers
__launch_bounds__(256)
__global__ void softmax_rows4(u16* __restrict__ sc) {
    int row = blockIdx.x * 4 + (threadIdx.x >> 6);
    int lane = threadIdx.x & 63;
    u16* p = sc + (long)row * 1024 + lane * 16;
    float v[16]; float mx = -1e30f;
    #pragma unroll
    for (int i = 0; i < 16; i++) { v[i] = bf2f(p[i]); mx = fmaxf(mx, v[i]); }
    #pragma unroll
    for (int o = 32; o > 0; o >>= 1) mx = fmaxf(mx, __shfl_xor(mx, o, 64));
    float s = 0.f;
    #pragma unroll
    for (int i = 0; i < 16; i++) { v[i] = expf(v[i] - mx); s += v[i]; }
    #pragma unroll
    for (int o = 32; o > 0; o >>= 1) s += __shfl_xor(s, o, 64);
    float r = 1.0f / s;
    #pragma unroll
    for (int i = 0; i < 16; i++) p[i] = f2bf(v[i] * r);
}
__global__ void final_out(const float* __restrict__ x2, const float* __restrict__ scale,
                          const float* __restrict__ inv2, const u16* __restrict__ g,
                          const u16* __restrict__ l, const float* __restrict__ beta,
                          float* __restrict__ out) {
    long i = (long)blockIdx.x * 256 + threadIdx.x;
    int b = (int)(i >> 19), md = (int)(i & 524287);
    float x3 = x2[i] * inv2[b] * scale[md];
    float gv = bf2f(g[i]), lv = bf2f(l[i]);
    float bta = beta[0];
    float sw = gv / (1.0f + expf(-bta * gv));
    out[i] = x3 + sw * lv;
}
__global__ void convert_f2b(const float* __restrict__ s, u16* __restrict__ d, int n) {
    int i = blockIdx.x * 256 + threadIdx.x;
    if (i < n) d[i] = f2bf(s[i]);
}
__global__ void convert3(const float* __restrict__ a, const float* __restrict__ b,
                         const float* __restrict__ c, u16* __restrict__ d) {
    int i = blockIdx.x * 256 + threadIdx.x;      // [0, 786432)
    const float* s = (i < 262144) ? a : (i < 524288) ? b : c;
    d[i] = f2bf(s[i & 262143]);
}

// ---------------- host ----------------
#define MB 1048576L
extern "C" void kernel_launch(void* const* d_in, const int* in_sizes, int n_in,
                              void* d_out, int out_size, void* d_ws, size_t ws_size,
                              hipStream_t stream) {
    (void)in_sizes; (void)n_in; (void)out_size;
    const float* x    = (const float*)d_in[0];
    const float* scale= (const float*)d_in[1];
    const float* Wq   = (const float*)d_in[2];
    const float* Wk   = (const float*)d_in[3];
    const float* Wv   = (const float*)d_in[4];
    const float* Wo   = (const float*)d_in[5];
    const float* bo   = (const float*)d_in[6];
    const float* Wff  = (const float*)d_in[7];
    const float* bff  = (const float*)d_in[8];
    const float* Wg   = (const float*)d_in[9];
    const float* bg   = (const float*)d_in[10];
    const float* Wl   = (const float*)d_in[11];
    const float* bl   = (const float*)d_in[12];
    const float* beta = (const float*)d_in[13];
    float* out = (float*)d_out;
    char* ws = (char*)d_ws;
    const float sscale = 0.044194173824159216f;  // 1/sqrt(512)

    if (ws_size >= 240 * MB) {
        // ================= tier A: all-head batched (239.5 MiB) =================
        u16*   xnb   = (u16*)  (ws);             //   8 MiB bf16 xn (b,m,d)
        float* x2    = (float*)(ws + 8*MB);      //  16 MiB fp32 accum
        u16*   q_all = (u16*)  (ws + 24*MB);     //  64 MiB (h,b,m,512) -> cat
        u16*   k_all = (u16*)  (ws + 88*MB);     //  64 MiB -> FF scratch
        u16*   vT_all= (u16*)  (ws + 152*MB);    //  64 MiB (h,b,512,1024)
        u16*   sc    = (u16*)  (ws + 216*MB);    //  16 MiB per-head scores
        u16*   Wqkvb = (u16*)  (ws + 216*MB);    //  12 MiB (dead before sc used)
        u16*   Wob   = (u16*)  (ws + 232*MB);    //   4 MiB
        u16*   Wffb  = (u16*)  (ws + 236*MB);    //  0.5 MiB
        u16*   Wglb  = (u16*)  (ws + 236*MB + 524288L);  // 1 MiB [Wg;Wl]
        float* cosT  = (float*)(ws + 237*MB + 1572864L); // 1 MiB
        float* sinT  = (float*)(ws + 238*MB + 1572864L); // 1 MiB
        float* part  = (float*)(ws + 239*MB + 1572864L);
        float* inv1  = part + 512;
        float* inv2  = part + 528;
        // FF scratch in k_all region:
        u16* x3b = k_all; u16* h1 = k_all + 4194304; u16* g = k_all + 8388608; u16* l = k_all + 12582912;

        sumsq_f32<<<dim3(8, 64), 256, 0, stream>>>(x, part);
        finalize_inv<<<8, 64, 0, stream>>>(part, inv1);
        rmsnorm1f<<<16384, 256, 0, stream>>>(x, scale, inv1, bo, xnb, x2);
        rope_tables<<<1024, 256, 0, stream>>>(cosT, sinT);
        convert_f2b<<<8192, 256, 0, stream>>>(Wq, Wqkvb, 2097152);
        convert_f2b<<<8192, 256, 0, stream>>>(Wk, Wqkvb + 2097152, 2097152);
        convert_f2b<<<8192, 256, 0, stream>>>(Wv, Wqkvb + 4194304, 2097152);
        convert_f2b<<<8192, 256, 0, stream>>>(Wo, Wob, 2097152);
        convert_f2b<<<1024, 256, 0, stream>>>(Wff, Wffb, 262144);
        convert_f2b<<<1024, 256, 0, stream>>>(Wg, Wglb, 262144);
        convert_f2b<<<1024, 256, 0, stream>>>(Wl, Wglb + 262144, 262144);

        // QKV all heads, rope fused in epilogue, V stored transposed. z = which*8+h.
        gemm128<<<dim3(64, 4, 24), 256, 0, stream>>>(xnb, Wqkvb, 512, 1, 512, 512,
            0L, 262144L, 0L, EpiQKV{q_all, k_all, vT_all, cosT, sinT});

        for (int h = 0; h < 8; h++) {
            const u16* qh = q_all + (long)h * 4194304;
            const u16* kh = k_all + (long)h * 4194304;
            const u16* vTh = vT_all + (long)h * 4194304;
            u16* cath = q_all + (long)h * 4194304;        // overwrite q slice after use
            gemm128<<<dim3(8, 8, 8), 256, 0, stream>>>(qh, kh, 512, 1, 512, 512,
                524288L, 524288L, 0L, EpiScale{sc, 1048576L, 1024, sscale});
            softmax_rows4<<<2048, 256, 0, stream>>>(sc);
            gemm128<<<dim3(8, 4, 8), 256, 0, stream>>>(sc, vTh, 1024, 1, 1024, 1024,
                1048576L, 524288L, 0L, EpiBF16{cath, 524288L, 512});
        }
        // x2 += cat @ Wo^T, segmented K = 8 x 512 (segment s = head s at aSeg stride)
        gemm128<<<dim3(64, 4, 1), 256, 0, stream>>>(q_all, Wob, 512, 8, 512, 4096,
            0L, 0L, 4194304L, EpiAcc{x2});

        sumsq_f32<<<dim3(8, 64), 256, 0, stream>>>(x2, part);
        finalize_inv<<<8, 64, 0, stream>>>(part, inv2);
        rmsnorm2<<<16384, 256, 0, stream>>>(x2, scale, inv2, x3b);

        gemm128<<<dim3(64, 4, 1), 256, 0, stream>>>(x3b, Wffb, 512, 1, 512, 512,
            0L, 0L, 0L, EpiBias16{h1, bff});
        gemm128<<<dim3(64, 8, 1), 256, 0, stream>>>(h1, Wglb, 512, 1, 512, 512,
            0L, 0L, 0L, EpiGL{g, l, bg, bl});
        final_out<<<16384, 256, 0, stream>>>(x2, scale, inv2, g, l, beta, out);
        return;
    }

    // ================= tier B/C: per-head loop (<= 86 MiB) =================
    u16*   xnb  = (u16*)  (ws);                  //  8 MiB
    float* x2   = (float*)(ws + 8388608L);       // 16 MiB
    u16*   qh   = (u16*)  (ws + 25165824L);      //  8 MiB
    u16*   kh   = (u16*)  (ws + 33554432L);      //  8 MiB (contiguous after qh)
    u16*   vhc  = (u16*)  (ws + 41943040L);      //  8 MiB v, then ctx
    u16*   vT   = (u16*)  (ws + 50331648L);      //  8 MiB
    u16*   Whb  = (u16*)  (ws + 58720256L);      //  1.5 MiB
    u16*   Wob  = (u16*)  (ws + 60293120L);      //  4 MiB
    u16*   Wfb  = (u16*)  (ws + 64487424L);      //  0.5 MiB
    u16*   Wgb  = (u16*)  (ws + 65011712L);      //  0.5 MiB
    u16*   Wlb  = (u16*)  (ws + 65536000L);      //  0.5 MiB
    float* cosT = (float*)(ws + 66060288L);      //  1 MiB
    float* sinT = (float*)(ws + 67108864L);      //  1 MiB
    float* part = (float*)(ws + 68157440L);
    float* inv1 = (float*)(ws + 68159488L);
    float* inv2 = (float*)(ws + 68159552L);
    u16*   sc   = (u16*)  (ws + 68159616L);      // 16 MiB (big) / 2 MiB (small)
    u16*   x3b = qh;  u16* h1 = kh;  u16* g = vhc;  u16* l = vT;
    const bool big = ws_size >= 85002240UL;

    sumsq_f32<<<dim3(8, 64), 256, 0, stream>>>(x, part);
    finalize_inv<<<8, 64, 0, stream>>>(part, inv1);
    rmsnorm1f<<<16384, 256, 0, stream>>>(x, scale, inv1, bo, xnb, x2);
    rope_tables<<<1024, 256, 0, stream>>>(cosT, sinT);
    convert_f2b<<<8192, 256, 0, stream>>>(Wo, Wob, 2097152);
    convert_f2b<<<1024, 256, 0, stream>>>(Wff, Wfb, 262144);
    convert_f2b<<<1024, 256, 0, stream>>>(Wg, Wgb, 262144);
    convert_f2b<<<1024, 256, 0, stream>>>(Wl, Wlb, 262144);

    for (int h = 0; h < 8; h++) {
        convert3<<<3072, 256, 0, stream>>>(Wq + (long)h * 262144, Wk + (long)h * 262144,
                                           Wv + (long)h * 262144, Whb);
        gemm128<<<dim3(64, 4, 3), 256, 0, stream>>>(xnb, Whb, 512, 1, 512, 512, 0L, 262144L, 0L,
                                                    EpiBF16{qh, 4194304L, 512});
        rope_apply<<<16384, 256, 0, stream>>>(qh, cosT, sinT);   // q and k ONLY (4M pairs)
        transpose_v<<<dim3(32, 16, 8), 256, 0, stream>>>(vhc, vT);
        if (big) {
            gemm128<<<dim3(8, 8, 8), 256, 0, stream>>>(qh, kh, 512, 1, 512, 512, 524288L, 524288L,
                                                       0L, EpiScale{sc, 1048576L, 1024, sscale});
            softmax_rows4<<<2048, 256, 0, stream>>>(sc);
            gemm128<<<dim3(8, 4, 8), 256, 0, stream>>>(sc, vT, 1024, 1, 1024, 1024, 1048576L,
                                                       524288L, 0L, EpiBF16{vhc, 524288L, 512});
        } else {
            for (int b = 0; b < 8; b++) {
                gemm128<<<dim3(8, 8, 1), 256, 0, stream>>>(qh + (long)b * 524288, kh + (long)b * 524288,
                                                           512, 1, 512, 512, 0L, 0L, 0L,
                                                           EpiScale{sc, 0L, 1024, sscale});
                softmax_rows4<<<256, 256, 0, stream>>>(sc);
                gemm128<<<dim3(8, 4, 1), 256, 0, stream>>>(sc, vT + (long)b * 524288, 1024, 1, 1024,
                                                           1024, 0L, 0L, 0L,
                                                           EpiBF16{vhc + (long)b * 524288, 0L, 512});
            }
        }
        gemm128<<<dim3(64, 4, 1), 256, 0, stream>>>(vhc, Wob + (long)h * 512, 512, 1, 512, 4096,
                                                    0L, 0L, 0L, EpiAcc{x2});
    }

    sumsq_f32<<<dim3(8, 64), 256, 0, stream>>>(x2, part);
    finalize_inv<<<8, 64, 0, stream>>>(part, inv2);
    rmsnorm2<<<16384, 256, 0, stream>>>(x2, scale, inv2, x3b);
    gemm128<<<dim3(64, 4, 1), 256, 0, stream>>>(x3b, Wfb, 512, 1, 512, 512, 0L, 0L, 0L,
                                                EpiBias16{h1, bff});
    gemm128<<<dim3(64, 4, 1), 256, 0, stream>>>(h1, Wgb, 512, 1, 512, 512, 0L, 0L, 0L,
                                                EpiBias16{g, bg});
    gemm128<<<dim3(64, 4, 1), 256, 0, stream>>>(h1, Wlb, 512, 1, 512, 512, 0L, 0L, 0L,
                                                EpiBias16{l, bl});
    final_out<<<16384, 256, 0, stream>>>(x2, scale, inv2, g, l, beta, out);
}

// Round 8
// 887.452 us; speedup vs baseline: 1.5059x; 1.0383x over previous
//
#include <hip/hip_runtime.h>
#include <math.h>

typedef unsigned short u16;
typedef float f32x4 __attribute__((ext_vector_type(4)));
typedef __bf16 bf16x8 __attribute__((ext_vector_type(8)));

__device__ __forceinline__ float bf2f(u16 u) {
    union { float f; unsigned int i; } v; v.i = ((unsigned int)u) << 16; return v.f;
}
__device__ __forceinline__ u16 f2bf(float f) {
    union { float f; unsigned int i; } v; v.f = f;
    unsigned int r = v.i + 0x7fffu + ((v.i >> 16) & 1u);
    return (u16)(r >> 16);
}

// async global->LDS, 16B per lane. LDS dest is wave-uniform base + lane*16.
__device__ __forceinline__ void gll(const u16* g, u16* l) {
    __builtin_amdgcn_global_load_lds((const __attribute__((address_space(1))) void*)g,
                                     (__attribute__((address_space(3))) void*)l, 16, 0, 0);
}

// ---------------- epilogue functors ----------------
struct EpiBF16 {            // bf16 store with batch stride
    u16* C; long zs; int ldc;
    __device__ void operator()(int z, int m, int n, float v) const {
        C[(long)z * zs + (long)m * ldc + n] = f2bf(v);
    }
};
struct EpiScale {           // scores: scale then bf16 store
    u16* C; long zs; int ldc; float s;
    __device__ void operator()(int z, int m, int n, float v) const {
        C[(long)z * zs + (long)m * ldc + n] = f2bf(v * s);
    }
};
struct EpiAcc {             // x2 += v  (fp32, 512-wide rows)
    float* x2;
    __device__ void operator()(int z, int m, int n, float v) const {
        x2[(long)m * 512 + n] += v;
    }
};
struct EpiBias16 {          // v + fp32 bias -> bf16
    u16* C; const float* bias;
    __device__ void operator()(int z, int m, int n, float v) const {
        C[(long)m * 512 + n] = f2bf(v + bias[n]);
    }
};
struct EpiGL {              // split N=1024 into g (n<512) and l, with biases
    u16* g; u16* l; const float* bg; const float* bl;
    __device__ void operator()(int z, int m, int n, float v) const {
        if (n < 512) g[(long)m * 512 + n] = f2bf(v + bg[n]);
        else         l[(long)m * 512 + n - 512] = f2bf(v + bl[n - 512]);
    }
};
struct EpiZ3 {              // z = which*8+h -> plain coalesced store into q/k/v
    u16* q; u16* k; u16* v;
    __device__ void operator()(int z, int m, int n, float val) const {
        int which = z >> 3, h = z & 7;
        u16* dst = (which == 0) ? q : (which == 1) ? k : v;
        dst[(long)h * 4194304 + (long)m * 512 + n] = f2bf(val);
    }
};

// ------- GEMM 128x128 tile, BK=64 (2 x 32 sub-tiles per barrier pair).
// C[m,n] = sum_{s,k} A[m, s,k]*B[n, s*Kseg+k]; global_load_lds(16B) staging,
// unpadded LDS + XOR column swizzle, 4 waves, wave = 4x4 frags of 16x16x32.
// Kseg must be a multiple of 64. Segmented K: nSeg segments of Kseg.
template <class Epi>
__launch_bounds__(256, 4)
__global__ void gemm128(const u16* __restrict__ A, const u16* __restrict__ B,
                        int Kseg, int nSeg, int lda, int ldb,
                        long aBatch, long bBatch, long aSeg, Epi epi) {
    __shared__ __align__(16) u16 sA[8192];   // 128 x 64 (two 128x32 sub-tiles)
    __shared__ __align__(16) u16 sB[8192];
    const int t = threadIdx.x;
    const int lane = t & 63, wave = t >> 6;
    const int wr = wave >> 1, wc = wave & 1;
    const int l15 = lane & 15, quad = lane >> 4;
    const int m0 = blockIdx.x * 128, n0 = blockIdx.y * 128;
    const int sr = t >> 2;
    const int scw = ((t & 3) ^ ((t >> 3) & 3)) * 8;
    const u16* gA = A + (long)blockIdx.z * aBatch + (long)(m0 + sr) * lda + scw;
    const u16* gB = B + (long)blockIdx.z * bBatch + (long)(n0 + sr) * ldb + scw;
    const long a2 = 64L * lda, b2 = 64L * ldb;
    u16* lA = sA + wave * 512 + lane * 8;
    u16* lB = sB + wave * 512 + lane * 8;
    const int ap = (quad ^ ((l15 >> 1) & 3)) * 8;
    const int ab = (wr * 64 + l15) * 32 + ap;
    const int bb = (wc * 64 + l15) * 32 + ap;
    f32x4 acc[4][4] = {};
    for (int s = 0; s < nSeg; s++) {
        const u16* gAs = gA + (long)s * aSeg;
        const u16* gBs = gB + s * Kseg;
        for (int k0 = 0; k0 < Kseg; k0 += 64) {
            // sub-tile 0: cols k0..k0+32 ; sub-tile 1: cols k0+32..k0+64
            gll(gAs + k0, lA);            gll(gAs + k0 + a2, lA + 2048);
            gll(gBs + k0, lB);            gll(gBs + k0 + b2, lB + 2048);
            gll(gAs + k0 + 32, lA + 4096); gll(gAs + k0 + 32 + a2, lA + 6144);
            gll(gBs + k0 + 32, lB + 4096); gll(gBs + k0 + 32 + b2, lB + 6144);
            __syncthreads();
            {
                bf16x8 aF[4], bF[4];
                #pragma unroll
                for (int i = 0; i < 4; i++) aF[i] = *(const bf16x8*)(sA + ab + i * 512);
                #pragma unroll
                for (int j = 0; j < 4; j++) bF[j] = *(const bf16x8*)(sB + bb + j * 512);
                #pragma unroll
                for (int i = 0; i < 4; i++)
                    #pragma unroll
                    for (int j = 0; j < 4; j++)
                        acc[i][j] = __builtin_amdgcn_mfma_f32_16x16x32_bf16(aF[i], bF[j], acc[i][j], 0, 0, 0);
            }
            {
                bf16x8 aF[4], bF[4];
                #pragma unroll
                for (int i = 0; i < 4; i++) aF[i] = *(const bf16x8*)(sA + 4096 + ab + i * 512);
                #pragma unroll
                for (int j = 0; j < 4; j++) bF[j] = *(const bf16x8*)(sB + 4096 + bb + j * 512);
                #pragma unroll
                for (int i = 0; i < 4; i++)
                    #pragma unroll
                    for (int j = 0; j < 4; j++)
                        acc[i][j] = __builtin_amdgcn_mfma_f32_16x16x32_bf16(aF[i], bF[j], acc[i][j], 0, 0, 0);
            }
            __syncthreads();
        }
    }
    #pragma unroll
    for (int i = 0; i < 4; i++)
        #pragma unroll
        for (int j = 0; j < 4; j++)
            #pragma unroll
            for (int r = 0; r < 4; r++)
                epi(blockIdx.z, m0 + wr * 64 + i * 16 + quad * 4 + r,   // row=(lane>>4)*4+reg
                    n0 + wc * 64 + j * 16 + l15, acc[i][j][r]);         // col=lane&15
}

// ---------------- reductions / elementwise ----------------
__device__ __forceinline__ float waveSum(float v) {
    #pragma unroll
    for (int o = 32; o > 0; o >>= 1) v += __shfl_down(v, o, 64);
    return v;
}

__global__ void sumsq_f32(const float* __restrict__ x, float* __restrict__ part) {
    __shared__ float tmp[4];
    long base = (long)blockIdx.x * 524288 + (long)blockIdx.y * 8192;
    float s = 0.f;
    for (int i = threadIdx.x; i < 8192; i += 256) { float v = x[base + i]; s += v * v; }
    s = waveSum(s);
    if ((threadIdx.x & 63) == 0) tmp[threadIdx.x >> 6] = s;
    __syncthreads();
    if (threadIdx.x == 0) part[blockIdx.x * 64 + blockIdx.y] = tmp[0] + tmp[1] + tmp[2] + tmp[3];
}
__global__ void finalize_inv(const float* __restrict__ part, float* __restrict__ inv) {
    float s = part[blockIdx.x * 64 + threadIdx.x];
    s = waveSum(s);
    if (threadIdx.x == 0) inv[blockIdx.x] = sqrtf(524288.0f / s);  // 1/ff_rms
}
__global__ void rmsnorm1f(const float* __restrict__ x, const float* __restrict__ scale,
                          const float* __restrict__ inv, const float* __restrict__ bo,
                          u16* __restrict__ xnb, float* __restrict__ x2) {
    long i = (long)blockIdx.x * 256 + threadIdx.x;
    int b = (int)(i >> 19), md = (int)(i & 524287);
    float v = x[i] * inv[b] * scale[md];
    xnb[i] = f2bf(v);
    x2[i] = v + bo[i & 511];
}
__global__ void rmsnorm2(const float* __restrict__ x2, const float* __restrict__ scale,
                         const float* __restrict__ inv, u16* __restrict__ x3b) {
    long i = (long)blockIdx.x * 256 + threadIdx.x;
    int b = (int)(i >> 19), md = (int)(i & 524287);
    x3b[i] = f2bf(x2[i] * inv[b] * scale[md]);
}
__global__ void rope_tables(float* __restrict__ cosT, float* __restrict__ sinT) {
    int i = blockIdx.x * 256 + threadIdx.x;      // 1024*256
    int m = i >> 8, j = i & 255;
    float theta = powf(10000.0f, -2.0f * ((float)j - 1.0f) / 512.0f);
    float ang = (float)m * theta;
    cosT[i] = cosf(ang); sinT[i] = sinf(ang);
}
__global__ void rope_apply(u16* __restrict__ tq, const float* __restrict__ cosT,
                           const float* __restrict__ sinT) {
    long i = (long)blockIdx.x * 256 + threadIdx.x;
    int j = (int)(i & 255), m = (int)((i >> 8) & 1023);
    float c = cosT[m * 256 + j], s = sinT[m * 256 + j];
    long base = i * 2;
    float te = bf2f(tq[base]), to = bf2f(tq[base + 1]);
    tq[base]     = f2bf(te * c + to * s);
    tq[base + 1] = f2bf(-te * s + to * c);
}
__global__ void transpose_v(const u16* __restrict__ v, u16* __restrict__ vT) {
    __shared__ u16 tile[32][33];
    long zb = (long)blockIdx.z * 524288;
    int mo = blockIdx.x * 32, oo = blockIdx.y * 32;
    int tx = threadIdx.x & 31, ty = threadIdx.x >> 5;
    for (int r = ty; r < 32; r += 8) tile[r][tx] = v[zb + (long)(mo + r) * 512 + oo + tx];
    __syncthreads();
    for (int r = ty; r < 32; r += 8) vT[zb + (long)(oo + r) * 1024 + mo + tx] = tile[tx][r];
}
// wave-per-row softmax: grid = rows/4, block 256 (4 waves), no barriers
__launch_bounds__(256)
__global__ void softmax_rows4(u16* __restrict__ sc) {
    int row = blockIdx.x * 4 + (threadIdx.x >> 6);
    int lane = threadIdx.x & 63;
    u16* p = sc + (long)row * 1024 + lane * 16;
    float v[16]; float mx = -1e30f;
    #pragma unroll
    for (int i = 0; i < 16; i++) { v[i] = bf2f(p[i]); mx = fmaxf(mx, v[i]); }
    #pragma unroll
    for (int o = 32; o > 0; o >>= 1) mx = fmaxf(mx, __shfl_xor(mx, o, 64));
    float s = 0.f;
    #pragma unroll
    for (int i = 0; i < 16; i++) { v[i] = expf(v[i] - mx); s += v[i]; }
    #pragma unroll
    for (int o = 32; o > 0; o >>= 1) s += __shfl_xor(s, o, 64);
    float r = 1.0f / s;
    #pragma unroll
    for (int i = 0; i < 16; i++) p[i] = f2bf(v[i] * r);
}
__global__ void final_out(const float* __restrict__ x2, const float* __restrict__ scale,
                          const float* __restrict__ inv2, const u16* __restrict__ g,
                          const u16* __restrict__ l, const float* __restrict__ beta,
                          float* __restrict__ out) {
    long i = (long)blockIdx.x * 256 + threadIdx.x;
    int b = (int)(i >> 19), md = (int)(i & 524287);
    float x3 = x2[i] * inv2[b] * scale[md];
    float gv = bf2f(g[i]), lv = bf2f(l[i]);
    float bta = beta[0];
    float sw = gv / (1.0f + expf(-bta * gv));
    out[i] = x3 + sw * lv;
}
__global__ void convert_f2b(const float* __restrict__ s, u16* __restrict__ d, int n) {
    int i = blockIdx.x * 256 + threadIdx.x;
    if (i < n) d[i] = f2bf(s[i]);
}
__global__ void convert3(const float* __restrict__ a, const float* __restrict__ b,
                         const float* __restrict__ c, u16* __restrict__ d) {
    int i = blockIdx.x * 256 + threadIdx.x;      // [0, 786432)
    const float* s = (i < 262144) ? a : (i < 524288) ? b : c;
    d[i] = f2bf(s[i & 262143]);
}

// ---------------- host ----------------
#define MB 1048576L
extern "C" void kernel_launch(void* const* d_in, const int* in_sizes, int n_in,
                              void* d_out, int out_size, void* d_ws, size_t ws_size,
                              hipStream_t stream) {
    (void)in_sizes; (void)n_in; (void)out_size;
    const float* x    = (const float*)d_in[0];
    const float* scale= (const float*)d_in[1];
    const float* Wq   = (const float*)d_in[2];
    const float* Wk   = (const float*)d_in[3];
    const float* Wv   = (const float*)d_in[4];
    const float* Wo   = (const float*)d_in[5];
    const float* bo   = (const float*)d_in[6];
    const float* Wff  = (const float*)d_in[7];
    const float* bff  = (const float*)d_in[8];
    const float* Wg   = (const float*)d_in[9];
    const float* bg   = (const float*)d_in[10];
    const float* Wl   = (const float*)d_in[11];
    const float* bl   = (const float*)d_in[12];
    const float* beta = (const float*)d_in[13];
    float* out = (float*)d_out;
    char* ws = (char*)d_ws;
    const float sscale = 0.044194173824159216f;  // 1/sqrt(512)

    if (ws_size >= 260000000UL) {
        // ===== tier A: plain QKV stores + separate rope + per-head transpose =====
        u16*   xnb   = (u16*)  (ws);                 //   8 MiB bf16 xn
        float* x2    = (float*)(ws + 8388608L);      //  16 MiB fp32 accum
        u16*   q_all = (u16*)  (ws + 25165824L);     //  64 MiB (h,b,m,512) -> cat
        u16*   k_all = (u16*)  (ws + 92274688L);     //  64 MiB (adjacent to q)
        u16*   v_all = (u16*)  (ws + 159383552L);    //  64 MiB
        u16*   vT_h  = (u16*)  (ws + 226492416L);    //   8 MiB per-head scratch
        u16*   sc    = (u16*)  (ws + 234881024L);    //  16 MiB per-head scores
        u16*   Wqkvb = (u16*)  (ws + 226492416L);    //  12.6 MiB (dead before vT/sc used)
        u16*   Wob   = (u16*)  (ws + 251658240L);    //   4 MiB
        u16*   Wffb  = (u16*)  (ws + 255852544L);    //  0.5 MiB
        u16*   Wglb  = (u16*)  (ws + 256376832L);    //   1 MiB [Wg;Wl]
        float* cosT  = (float*)(ws + 257425408L);    //   1 MiB
        float* sinT  = (float*)(ws + 258473984L);    //   1 MiB
        float* part  = (float*)(ws + 259522560L);
        float* inv1  = part + 512;
        float* inv2  = part + 528;
        // FF scratch in k_all region (dead after head loop):
        u16* x3b = k_all; u16* h1 = k_all + 4194304; u16* g = k_all + 8388608; u16* l = k_all + 12582912;

        sumsq_f32<<<dim3(8, 64), 256, 0, stream>>>(x, part);
        finalize_inv<<<8, 64, 0, stream>>>(part, inv1);
        rmsnorm1f<<<16384, 256, 0, stream>>>(x, scale, inv1, bo, xnb, x2);
        rope_tables<<<1024, 256, 0, stream>>>(cosT, sinT);
        convert_f2b<<<8192, 256, 0, stream>>>(Wq, Wqkvb, 2097152);
        convert_f2b<<<8192, 256, 0, stream>>>(Wk, Wqkvb + 2097152, 2097152);
        convert_f2b<<<8192, 256, 0, stream>>>(Wv, Wqkvb + 4194304, 2097152);
        convert_f2b<<<8192, 256, 0, stream>>>(Wo, Wob, 2097152);
        convert_f2b<<<1024, 256, 0, stream>>>(Wff, Wffb, 262144);
        convert_f2b<<<1024, 256, 0, stream>>>(Wg, Wglb, 262144);
        convert_f2b<<<1024, 256, 0, stream>>>(Wl, Wglb + 262144, 262144);

        // QKV all heads: z = which*8+h, plain coalesced stores
        gemm128<<<dim3(64, 4, 24), 256, 0, stream>>>(xnb, Wqkvb, 512, 1, 512, 512,
            0L, 262144L, 0L, EpiZ3{q_all, k_all, v_all});
        // rope q_all and k_all (adjacent, 32M pairs)
        rope_apply<<<131072, 256, 0, stream>>>(q_all, cosT, sinT);

        for (int h = 0; h < 8; h++) {
            const u16* qh = q_all + (long)h * 4194304;
            const u16* kh = k_all + (long)h * 4194304;
            u16* cath = q_all + (long)h * 4194304;        // overwrite q slice after use
            transpose_v<<<dim3(32, 16, 8), 256, 0, stream>>>(v_all + (long)h * 4194304, vT_h);
            gemm128<<<dim3(8, 8, 8), 256, 0, stream>>>(qh, kh, 512, 1, 512, 512,
                524288L, 524288L, 0L, EpiScale{sc, 1048576L, 1024, sscale});
            softmax_rows4<<<2048, 256, 0, stream>>>(sc);
            gemm128<<<dim3(8, 4, 8), 256, 0, stream>>>(sc, vT_h, 1024, 1, 1024, 1024,
                1048576L, 524288L, 0L, EpiBF16{cath, 524288L, 512});
        }
        // x2 += cat @ Wo^T, segmented K = 8 x 512 (segment s = head s at aSeg stride)
        gemm128<<<dim3(64, 4, 1), 256, 0, stream>>>(q_all, Wob, 512, 8, 512, 4096,
            0L, 0L, 4194304L, EpiAcc{x2});

        sumsq_f32<<<dim3(8, 64), 256, 0, stream>>>(x2, part);
        finalize_inv<<<8, 64, 0, stream>>>(part, inv2);
        rmsnorm2<<<16384, 256, 0, stream>>>(x2, scale, inv2, x3b);

        gemm128<<<dim3(64, 4, 1), 256, 0, stream>>>(x3b, Wffb, 512, 1, 512, 512,
            0L, 0L, 0L, EpiBias16{h1, bff});
        gemm128<<<dim3(64, 8, 1), 256, 0, stream>>>(h1, Wglb, 512, 1, 512, 512,
            0L, 0L, 0L, EpiGL{g, l, bg, bl});
        final_out<<<16384, 256, 0, stream>>>(x2, scale, inv2, g, l, beta, out);
        return;
    }

    // ================= tier B/C: per-head loop (<= 86 MiB) =================
    u16*   xnb  = (u16*)  (ws);                  //  8 MiB
    float* x2   = (float*)(ws + 8388608L);       // 16 MiB
    u16*   qh   = (u16*)  (ws + 25165824L);      //  8 MiB
    u16*   kh   = (u16*)  (ws + 33554432L);      //  8 MiB (contiguous after qh)
    u16*   vhc  = (u16*)  (ws + 41943040L);      //  8 MiB v, then ctx
    u16*   vT   = (u16*)  (ws + 50331648L);      //  8 MiB
    u16*   Whb  = (u16*)  (ws + 58720256L);      //  1.5 MiB
    u16*   Wob  = (u16*)  (ws + 60293120L);      //  4 MiB
    u16*   Wfb  = (u16*)  (ws + 64487424L);      //  0.5 MiB
    u16*   Wgb  = (u16*)  (ws + 65011712L);      //  0.5 MiB
    u16*   Wlb  = (u16*)  (ws + 65536000L);      //  0.5 MiB
    float* cosT = (float*)(ws + 66060288L);      //  1 MiB
    float* sinT = (float*)(ws + 67108864L);      //  1 MiB
    float* part = (float*)(ws + 68157440L);
    float* inv1 = (float*)(ws + 68159488L);
    float* inv2 = (float*)(ws + 68159552L);
    u16*   sc   = (u16*)  (ws + 68159616L);      // 16 MiB (big) / 2 MiB (small)
    u16*   x3b = qh;  u16* h1 = kh;  u16* g = vhc;  u16* l = vT;
    const bool big = ws_size >= 85002240UL;

    sumsq_f32<<<dim3(8, 64), 256, 0, stream>>>(x, part);
    finalize_inv<<<8, 64, 0, stream>>>(part, inv1);
    rmsnorm1f<<<16384, 256, 0, stream>>>(x, scale, inv1, bo, xnb, x2);
    rope_tables<<<1024, 256, 0, stream>>>(cosT, sinT);
    convert_f2b<<<8192, 256, 0, stream>>>(Wo, Wob, 2097152);
    convert_f2b<<<1024, 256, 0, stream>>>(Wff, Wfb, 262144);
    convert_f2b<<<1024, 256, 0, stream>>>(Wg, Wgb, 262144);
    convert_f2b<<<1024, 256, 0, stream>>>(Wl, Wlb, 262144);

    for (int h = 0; h < 8; h++) {
        convert3<<<3072, 256, 0, stream>>>(Wq + (long)h * 262144, Wk + (long)h * 262144,
                                           Wv + (long)h * 262144, Whb);
        gemm128<<<dim3(64, 4, 3), 256, 0, stream>>>(xnb, Whb, 512, 1, 512, 512, 0L, 262144L, 0L,
                                                    EpiBF16{qh, 4194304L, 512});
        rope_apply<<<16384, 256, 0, stream>>>(qh, cosT, sinT);   // q and k ONLY (4M pairs)
        transpose_v<<<dim3(32, 16, 8), 256, 0, stream>>>(vhc, vT);
        if (big) {
            gemm128<<<dim3(8, 8, 8), 256, 0, stream>>>(qh, kh, 512, 1, 512, 512, 524288L, 524288L,
                                                       0L, EpiScale{sc, 1048576L, 1024, sscale});
            softmax_rows4<<<2048, 256, 0, stream>>>(sc);
            gemm128<<<dim3(8, 4, 8), 256, 0, stream>>>(sc, vT, 1024, 1, 1024, 1024, 1048576L,
                                                       524288L, 0L, EpiBF16{vhc, 524288L, 512});
        } else {
            for (int b = 0; b < 8; b++) {
                gemm128<<<dim3(8, 8, 1), 256, 0, stream>>>(qh + (long)b * 524288, kh + (long)b * 524288,
                                                           512, 1, 512, 512, 0L, 0L, 0L,
                                                           EpiScale{sc, 0L, 1024, sscale});
                softmax_rows4<<<256, 256, 0, stream>>>(sc);
                gemm128<<<dim3(8, 4, 1), 256, 0, stream>>>(sc, vT + (long)b * 524288, 1024, 1, 1024,
                                                           1024, 0L, 0L, 0L,
                                                           EpiBF16{vhc + (long)b * 524288, 0L, 512});
            }
        }
        gemm128<<<dim3(64, 4, 1), 256, 0, stream>>>(vhc, Wob + (long)h * 512, 512, 1, 512, 4096,
                                                    0L, 0L, 0L, EpiAcc{x2});
    }

    sumsq_f32<<<dim3(8, 64), 256, 0, stream>>>(x2, part);
    finalize_inv<<<8, 64, 0, stream>>>(part, inv2);
    rmsnorm2<<<16384, 256, 0, stream>>>(x2, scale, inv2, x3b);
    gemm128<<<dim3(64, 4, 1), 256, 0, stream>>>(x3b, Wfb, 512, 1, 512, 512, 0L, 0L, 0L,
                                                EpiBias16{h1, bff});
    gemm128<<<dim3(64, 4, 1), 256, 0, stream>>>(h1, Wgb, 512, 1, 512, 512, 0L, 0L, 0L,
                                                EpiBias16{g, bg});
    gemm128<<<dim3(64, 4, 1), 256, 0, stream>>>(h1, Wlb, 512, 1, 512, 512, 0L, 0L, 0L,
                                                EpiBias16{l, bl});
    final_out<<<16384, 256, 0, stream>>>(x2, scale, inv2, g, l, beta, out);
}

// Round 9
// 821.900 us; speedup vs baseline: 1.6260x; 1.0798x over previous
//
#include <hip/hip_runtime.h>
#include <math.h>

typedef unsigned short u16;
typedef float f32x4 __attribute__((ext_vector_type(4)));
typedef __bf16 bf16x8 __attribute__((ext_vector_type(8)));
typedef unsigned short u16x8 __attribute__((ext_vector_type(8)));

__device__ __forceinline__ float bf2f(u16 u) {
    union { float f; unsigned int i; } v; v.i = ((unsigned int)u) << 16; return v.f;
}
__device__ __forceinline__ u16 f2bf(float f) {
    union { float f; unsigned int i; } v; v.f = f;
    unsigned int r = v.i + 0x7fffu + ((v.i >> 16) & 1u);
    return (u16)(r >> 16);
}

// async global->LDS, 16B per lane. LDS dest is wave-uniform base + lane*16.
__device__ __forceinline__ void gll(const u16* g, u16* l) {
    __builtin_amdgcn_global_load_lds((const __attribute__((address_space(1))) void*)g,
                                     (__attribute__((address_space(3))) void*)l, 16, 0, 0);
}

// ---------------- epilogue functors ----------------
struct EpiBF16 {            // bf16 store with batch stride
    u16* C; long zs; int ldc;
    __device__ void operator()(int z, int m, int n, float v) const {
        C[(long)z * zs + (long)m * ldc + n] = f2bf(v);
    }
};
struct EpiScale {           // scores: scale then bf16 store
    u16* C; long zs; int ldc; float s;
    __device__ void operator()(int z, int m, int n, float v) const {
        C[(long)z * zs + (long)m * ldc + n] = f2bf(v * s);
    }
};
struct EpiAcc {             // x2 += v  (fp32, 512-wide rows)
    float* x2;
    __device__ void operator()(int z, int m, int n, float v) const {
        x2[(long)m * 512 + n] += v;
    }
};
struct EpiBias16 {          // v + fp32 bias -> bf16
    u16* C; const float* bias;
    __device__ void operator()(int z, int m, int n, float v) const {
        C[(long)m * 512 + n] = f2bf(v + bias[n]);
    }
};
struct EpiGL {              // split N=1024 into g (n<512) and l, with biases
    u16* g; u16* l; const float* bg; const float* bl;
    __device__ void operator()(int z, int m, int n, float v) const {
        if (n < 512) g[(long)m * 512 + n] = f2bf(v + bg[n]);
        else         l[(long)m * 512 + n - 512] = f2bf(v + bl[n - 512]);
    }
};
struct EpiQKV3 {            // z = which*8+h: q,k plain; v scattered to vT layout
    u16* q; u16* k; u16* vT;
    __device__ void operator()(int z, int m, int n, float val) const {
        int which = z >> 3, h = z & 7;
        u16 b = f2bf(val);
        if (which < 2) {
            u16* dst = which ? k : q;
            dst[((long)h << 22) + (long)m * 512 + n] = b;
        } else {
            vT[((long)h << 22) + ((long)(m >> 10) << 19) + ((long)n << 10) + (m & 1023)] = b;
        }
    }
};
struct EpiCtxMul {          // ctx: multiply by reciprocal rowsum, store bf16
    u16* C; const float* rr;    // rr[z*1024+m] = 1/rowsum
    __device__ void operator()(int z, int m, int n, float v) const {
        C[(long)z * 524288 + (long)m * 512 + n] = f2bf(v * rr[(long)z * 1024 + m]);
    }
};

// ------- GEMM 128x128 tile, BK=64 (2 x 32 sub-tiles per barrier pair).
// C[m,n] = sum_{s,k} A[m, s,k]*B[n, s*Kseg+k]; global_load_lds(16B) staging,
// unpadded LDS + XOR column swizzle, 4 waves, wave = 4x4 frags of 16x16x32.
template <class Epi>
__launch_bounds__(256, 4)
__global__ void gemm128(const u16* __restrict__ A, const u16* __restrict__ B,
                        int Kseg, int nSeg, int lda, int ldb,
                        long aBatch, long bBatch, long aSeg, Epi epi) {
    __shared__ __align__(16) u16 sA[8192];   // 128 x 64
    __shared__ __align__(16) u16 sB[8192];
    const int t = threadIdx.x;
    const int lane = t & 63, wave = t >> 6;
    const int wr = wave >> 1, wc = wave & 1;
    const int l15 = lane & 15, quad = lane >> 4;
    const int m0 = blockIdx.x * 128, n0 = blockIdx.y * 128;
    const int sr = t >> 2;
    const int scw = ((t & 3) ^ ((t >> 3) & 3)) * 8;
    const u16* gA = A + (long)blockIdx.z * aBatch + (long)(m0 + sr) * lda + scw;
    const u16* gB = B + (long)blockIdx.z * bBatch + (long)(n0 + sr) * ldb + scw;
    const long a2 = 64L * lda, b2 = 64L * ldb;
    u16* lA = sA + wave * 512 + lane * 8;
    u16* lB = sB + wave * 512 + lane * 8;
    const int ap = (quad ^ ((l15 >> 1) & 3)) * 8;
    const int ab = (wr * 64 + l15) * 32 + ap;
    const int bb = (wc * 64 + l15) * 32 + ap;
    f32x4 acc[4][4] = {};
    for (int s = 0; s < nSeg; s++) {
        const u16* gAs = gA + (long)s * aSeg;
        const u16* gBs = gB + s * Kseg;
        for (int k0 = 0; k0 < Kseg; k0 += 64) {
            gll(gAs + k0, lA);             gll(gAs + k0 + a2, lA + 2048);
            gll(gBs + k0, lB);             gll(gBs + k0 + b2, lB + 2048);
            gll(gAs + k0 + 32, lA + 4096); gll(gAs + k0 + 32 + a2, lA + 6144);
            gll(gBs + k0 + 32, lB + 4096); gll(gBs + k0 + 32 + b2, lB + 6144);
            __syncthreads();
            #pragma unroll
            for (int half = 0; half < 2; half++) {
                bf16x8 aF[4], bF[4];
                #pragma unroll
                for (int i = 0; i < 4; i++) aF[i] = *(const bf16x8*)(sA + half * 4096 + ab + i * 512);
                #pragma unroll
                for (int j = 0; j < 4; j++) bF[j] = *(const bf16x8*)(sB + half * 4096 + bb + j * 512);
                #pragma unroll
                for (int i = 0; i < 4; i++)
                    #pragma unroll
                    for (int j = 0; j < 4; j++)
                        acc[i][j] = __builtin_amdgcn_mfma_f32_16x16x32_bf16(aF[i], bF[j], acc[i][j], 0, 0, 0);
            }
            __syncthreads();
        }
    }
    #pragma unroll
    for (int i = 0; i < 4; i++)
        #pragma unroll
        for (int j = 0; j < 4; j++)
            #pragma unroll
            for (int r = 0; r < 4; r++)
                epi(blockIdx.z, m0 + wr * 64 + i * 16 + quad * 4 + r,   // row=(lane>>4)*4+reg
                    n0 + wc * 64 + j * 16 + l15, acc[i][j][r]);         // col=lane&15
}

// ------- scores kernel: C = exp(sscale * A B^T) (bf16), rowsum accumulated via atomics.
__launch_bounds__(256, 4)
__global__ void gemm_scores(const u16* __restrict__ A, const u16* __restrict__ B,
                            u16* __restrict__ C, float* __restrict__ rs, float sscale) {
    __shared__ __align__(16) u16 sA[8192];
    __shared__ __align__(16) u16 sB[8192];
    const int t = threadIdx.x;
    const int lane = t & 63, wave = t >> 6;
    const int wr = wave >> 1, wc = wave & 1;
    const int l15 = lane & 15, quad = lane >> 4;
    const int m0 = blockIdx.x * 128, n0 = blockIdx.y * 128;
    const int z = blockIdx.z;
    const int sr = t >> 2;
    const int scw = ((t & 3) ^ ((t >> 3) & 3)) * 8;
    const u16* gA = A + (long)z * 524288 + (long)(m0 + sr) * 512 + scw;
    const u16* gB = B + (long)z * 524288 + (long)(n0 + sr) * 512 + scw;
    u16* lA = sA + wave * 512 + lane * 8;
    u16* lB = sB + wave * 512 + lane * 8;
    const int ap = (quad ^ ((l15 >> 1) & 3)) * 8;
    const int ab = (wr * 64 + l15) * 32 + ap;
    const int bb = (wc * 64 + l15) * 32 + ap;
    f32x4 acc[4][4] = {};
    for (int k0 = 0; k0 < 512; k0 += 64) {
        gll(gA + k0, lA);             gll(gA + k0 + 32768, lA + 2048);
        gll(gB + k0, lB);             gll(gB + k0 + 32768, lB + 2048);
        gll(gA + k0 + 32, lA + 4096); gll(gA + k0 + 32 + 32768, lA + 6144);
        gll(gB + k0 + 32, lB + 4096); gll(gB + k0 + 32 + 32768, lB + 6144);
        __syncthreads();
        #pragma unroll
        for (int half = 0; half < 2; half++) {
            bf16x8 aF[4], bF[4];
            #pragma unroll
            for (int i = 0; i < 4; i++) aF[i] = *(const bf16x8*)(sA + half * 4096 + ab + i * 512);
            #pragma unroll
            for (int j = 0; j < 4; j++) bF[j] = *(const bf16x8*)(sB + half * 4096 + bb + j * 512);
            #pragma unroll
            for (int i = 0; i < 4; i++)
                #pragma unroll
                for (int j = 0; j < 4; j++)
                    acc[i][j] = __builtin_amdgcn_mfma_f32_16x16x32_bf16(aF[i], bF[j], acc[i][j], 0, 0, 0);
        }
        __syncthreads();
    }
    // exp + store + per-row partial sums
    u16* Cz = C + (long)z * 1048576;
    #pragma unroll
    for (int i = 0; i < 4; i++)
        #pragma unroll
        for (int r = 0; r < 4; r++) {
            int m = m0 + wr * 64 + i * 16 + quad * 4 + r;
            float p = 0.f;
            #pragma unroll
            for (int j = 0; j < 4; j++) {
                float e = expf(acc[i][j][r] * sscale);
                acc[i][j][r] = e;
                p += e;
                Cz[(long)m * 1024 + n0 + wc * 64 + j * 16 + l15] = f2bf(e);
            }
            p += __shfl_xor(p, 1, 64); p += __shfl_xor(p, 2, 64);
            p += __shfl_xor(p, 4, 64); p += __shfl_xor(p, 8, 64);
            if (l15 == 0) atomicAdd(rs + (long)z * 1024 + m, p);
        }
}

// ---------------- reductions / elementwise ----------------
__device__ __forceinline__ float waveSum(float v) {
    #pragma unroll
    for (int o = 32; o > 0; o >>= 1) v += __shfl_down(v, o, 64);
    return v;
}

__global__ void sumsq_f32(const float* __restrict__ x, float* __restrict__ part) {
    __shared__ float tmp[4];
    long base = (long)blockIdx.x * 524288 + (long)blockIdx.y * 8192;
    float s = 0.f;
    for (int i = threadIdx.x; i < 8192; i += 256) { float v = x[base + i]; s += v * v; }
    s = waveSum(s);
    if ((threadIdx.x & 63) == 0) tmp[threadIdx.x >> 6] = s;
    __syncthreads();
    if (threadIdx.x == 0) part[blockIdx.x * 64 + blockIdx.y] = tmp[0] + tmp[1] + tmp[2] + tmp[3];
}
__global__ void finalize_inv(const float* __restrict__ part, float* __restrict__ inv) {
    float s = part[blockIdx.x * 64 + threadIdx.x];
    s = waveSum(s);
    if (threadIdx.x == 0) inv[blockIdx.x] = sqrtf(524288.0f / s);  // 1/ff_rms
}
__global__ void rmsnorm1f(const float* __restrict__ x, const float* __restrict__ scale,
                          const float* __restrict__ inv, const float* __restrict__ bo,
                          u16* __restrict__ xnb, float* __restrict__ x2) {
    long i = (long)blockIdx.x * 256 + threadIdx.x;
    int b = (int)(i >> 19), md = (int)(i & 524287);
    float v = x[i] * inv[b] * scale[md];
    xnb[i] = f2bf(v);
    x2[i] = v + bo[i & 511];
}
__global__ void rmsnorm2(const float* __restrict__ x2, const float* __restrict__ scale,
                         const float* __restrict__ inv, u16* __restrict__ x3b) {
    long i = (long)blockIdx.x * 256 + threadIdx.x;
    int b = (int)(i >> 19), md = (int)(i & 524287);
    x3b[i] = f2bf(x2[i] * inv[b] * scale[md]);
}
__global__ void rope_tables(float* __restrict__ cosT, float* __restrict__ sinT) {
    int i = blockIdx.x * 256 + threadIdx.x;      // 1024*256
    int m = i >> 8, j = i & 255;
    float theta = powf(10000.0f, -2.0f * ((float)j - 1.0f) / 512.0f);
    float ang = (float)m * theta;
    cosT[i] = cosf(ang); sinT[i] = sinf(ang);
}
__global__ void rope_apply(u16* __restrict__ tq, const float* __restrict__ cosT,
                           const float* __restrict__ sinT) {
    long i = (long)blockIdx.x * 256 + threadIdx.x;
    int j = (int)(i & 255), m = (int)((i >> 8) & 1023);
    float c = cosT[m * 256 + j], s = sinT[m * 256 + j];
    long base = i * 2;
    float te = bf2f(tq[base]), to = bf2f(tq[base + 1]);
    tq[base]     = f2bf(te * c + to * s);
    tq[base + 1] = f2bf(-te * s + to * c);
}
// vectorized rope: 8 elements (4 pairs) per thread, 16B loads/stores
__global__ void rope_v(u16* __restrict__ tq, const float* __restrict__ cosT,
                       const float* __restrict__ sinT) {
    long idx = (long)blockIdx.x * 256 + threadIdx.x;
    long base = idx * 8;
    int col = (int)(base & 511);         // multiple of 8
    int m = (int)((base >> 9) & 1023);
    int j0 = col >> 1;                   // multiple of 4
    f32x4 c = *(const f32x4*)(cosT + m * 256 + j0);
    f32x4 s = *(const f32x4*)(sinT + m * 256 + j0);
    u16x8 v = *(const u16x8*)(tq + base);
    u16x8 o;
    #pragma unroll
    for (int p = 0; p < 4; p++) {
        float te = bf2f(v[2 * p]), to = bf2f(v[2 * p + 1]);
        o[2 * p]     = f2bf(te * c[p] + to * s[p]);
        o[2 * p + 1] = f2bf(-te * s[p] + to * c[p]);
    }
    *(u16x8*)(tq + base) = o;
}
__global__ void transpose_v(const u16* __restrict__ v, u16* __restrict__ vT) {
    __shared__ u16 tile[32][33];
    long zb = (long)blockIdx.z * 524288;
    int mo = blockIdx.x * 32, oo = blockIdx.y * 32;
    int tx = threadIdx.x & 31, ty = threadIdx.x >> 5;
    for (int r = ty; r < 32; r += 8) tile[r][tx] = v[zb + (long)(mo + r) * 512 + oo + tx];
    __syncthreads();
    for (int r = ty; r < 32; r += 8) vT[zb + (long)(oo + r) * 1024 + mo + tx] = tile[tx][r];
}
// wave-per-row softmax (tier B/C only)
__launch_bounds__(256)
__global__ void softmax_rows4(u16* __restrict__ sc) {
    int row = blockIdx.x * 4 + (threadIdx.x >> 6);
    int lane = threadIdx.x & 63;
    u16* p = sc + (long)row * 1024 + lane * 16;
    float v[16]; float mx = -1e30f;
    #pragma unroll
    for (int i = 0; i < 16; i++) { v[i] = bf2f(p[i]); mx = fmaxf(mx, v[i]); }
    #pragma unroll
    for (int o = 32; o > 0; o >>= 1) mx = fmaxf(mx, __shfl_xor(mx, o, 64));
    float s = 0.f;
    #pragma unroll
    for (int i = 0; i < 16; i++) { v[i] = expf(v[i] - mx); s += v[i]; }
    #pragma unroll
    for (int o = 32; o > 0; o >>= 1) s += __shfl_xor(s, o, 64);
    float r = 1.0f / s;
    #pragma unroll
    for (int i = 0; i < 16; i++) p[i] = f2bf(v[i] * r);
}
__global__ void final_out(const float* __restrict__ x2, const float* __restrict__ scale,
                          const float* __restrict__ inv2, const u16* __restrict__ g,
                          const u16* __restrict__ l, const float* __restrict__ beta,
                          float* __restrict__ out) {
    long i = (long)blockIdx.x * 256 + threadIdx.x;
    int b = (int)(i >> 19), md = (int)(i & 524287);
    float x3 = x2[i] * inv2[b] * scale[md];
    float gv = bf2f(g[i]), lv = bf2f(l[i]);
    float bta = beta[0];
    float sw = gv / (1.0f + expf(-bta * gv));
    out[i] = x3 + sw * lv;
}
__global__ void convert_f2b(const float* __restrict__ s, u16* __restrict__ d, int n) {
    int i = blockIdx.x * 256 + threadIdx.x;
    if (i < n) d[i] = f2bf(s[i]);
}
__global__ void convert3(const float* __restrict__ a, const float* __restrict__ b,
                         const float* __restrict__ c, u16* __restrict__ d) {
    int i = blockIdx.x * 256 + threadIdx.x;
    const float* s = (i < 262144) ? a : (i < 524288) ? b : c;
    d[i] = f2bf(s[i & 262143]);
}
__global__ void zero_f32(float* __restrict__ p) {
    p[blockIdx.x * 256 + threadIdx.x] = 0.f;
}
__global__ void recip_f32(float* __restrict__ p) {
    int i = blockIdx.x * 256 + threadIdx.x;
    p[i] = 1.0f / p[i];
}

// ---------------- host ----------------
#define MB 1048576L
extern "C" void kernel_launch(void* const* d_in, const int* in_sizes, int n_in,
                              void* d_out, int out_size, void* d_ws, size_t ws_size,
                              hipStream_t stream) {
    (void)in_sizes; (void)n_in; (void)out_size;
    const float* x    = (const float*)d_in[0];
    const float* scale= (const float*)d_in[1];
    const float* Wq   = (const float*)d_in[2];
    const float* Wk   = (const float*)d_in[3];
    const float* Wv   = (const float*)d_in[4];
    const float* Wo   = (const float*)d_in[5];
    const float* bo   = (const float*)d_in[6];
    const float* Wff  = (const float*)d_in[7];
    const float* bff  = (const float*)d_in[8];
    const float* Wg   = (const float*)d_in[9];
    const float* bg   = (const float*)d_in[10];
    const float* Wl   = (const float*)d_in[11];
    const float* bl   = (const float*)d_in[12];
    const float* beta = (const float*)d_in[13];
    float* out = (float*)d_out;
    char* ws = (char*)d_ws;
    const float sscale = 0.044194173824159216f;  // 1/sqrt(512)

    if (ws_size >= 260000000UL) {
        // ===== tier A (~240 MiB): x2 lives in d_out; exp-scores + rowsum =====
        u16*   xnb   = (u16*)  (ws);                  //   8 MiB bf16 xn
        u16*   q_all = (u16*)  (ws + 8*MB);           //  64 MiB (h,b,m,512) -> cat
        u16*   k_all = (u16*)  (ws + 72*MB);          //  64 MiB (-> FF scratch)
        u16*   vT_all= (u16*)  (ws + 136*MB);         //  64 MiB (h,b,512,1024)
        u16*   sc    = (u16*)  (ws + 200*MB);         //  32 MiB (2-head expS chunk)
        u16*   Wqkvb = (u16*)  (ws + 200*MB);         //  12 MiB (dead before sc)
        u16*   Wob   = (u16*)  (ws + 232*MB);         //   4 MiB
        u16*   Wffb  = (u16*)  (ws + 236*MB);         //  0.5 MiB
        u16*   Wglb  = (u16*)  (ws + 236*MB + 524288L);   // 1 MiB [Wg;Wl]
        float* cosT  = (float*)(ws + 237*MB + 1572864L);  // 1 MiB
        float* sinT  = (float*)(ws + 238*MB + 1572864L);  // 1 MiB
        float* rowsum= (float*)(ws + 239*MB + 1572864L);  // 256 KiB (8h x 8b x 1024)
        float* part  = (float*)(ws + 239*MB + 1835008L);
        float* inv1  = part + 512;
        float* inv2  = part + 528;
        float* x2    = out;                            // 16 MiB fp32 in d_out
        // FF scratch in k_all region (dead after attention):
        u16* x3b = k_all; u16* h1 = k_all + 4194304; u16* g = k_all + 8388608; u16* l = k_all + 12582912;

        sumsq_f32<<<dim3(8, 64), 256, 0, stream>>>(x, part);
        finalize_inv<<<8, 64, 0, stream>>>(part, inv1);
        rmsnorm1f<<<16384, 256, 0, stream>>>(x, scale, inv1, bo, xnb, x2);
        rope_tables<<<1024, 256, 0, stream>>>(cosT, sinT);
        zero_f32<<<256, 256, 0, stream>>>(rowsum);
        convert_f2b<<<8192, 256, 0, stream>>>(Wq, Wqkvb, 2097152);
        convert_f2b<<<8192, 256, 0, stream>>>(Wk, Wqkvb + 2097152, 2097152);
        convert_f2b<<<8192, 256, 0, stream>>>(Wv, Wqkvb + 4194304, 2097152);
        convert_f2b<<<8192, 256, 0, stream>>>(Wo, Wob, 2097152);
        convert_f2b<<<1024, 256, 0, stream>>>(Wff, Wffb, 262144);
        convert_f2b<<<1024, 256, 0, stream>>>(Wg, Wglb, 262144);
        convert_f2b<<<1024, 256, 0, stream>>>(Wl, Wglb + 262144, 262144);

        // QKV all heads: q,k plain; v scattered into vT layout
        gemm128<<<dim3(64, 4, 24), 256, 0, stream>>>(xnb, Wqkvb, 512, 1, 512, 512,
            0L, 262144L, 0L, EpiQKV3{q_all, k_all, vT_all});
        // rope q_all+k_all (contiguous 128 MiB), vectorized
        rope_v<<<32768, 256, 0, stream>>>(q_all, cosT, sinT);

        // attention: 4 chunks of 2 heads; z = hl*8+b spans contiguous (h,b)
        for (int h0 = 0; h0 < 8; h0 += 2) {
            const long off = (long)h0 * 4194304;
            float* rsc = rowsum + (long)h0 * 8192;
            gemm_scores<<<dim3(8, 8, 16), 256, 0, stream>>>(q_all + off, k_all + off,
                                                            sc, rsc, sscale);
            recip_f32<<<64, 256, 0, stream>>>(rsc);
            gemm128<<<dim3(8, 4, 16), 256, 0, stream>>>(sc, vT_all + off, 1024, 1, 1024, 1024,
                1048576L, 524288L, 0L, EpiCtxMul{q_all + off, rsc});
        }
        // x2 += cat @ Wo^T, segmented K = 8 x 512
        gemm128<<<dim3(64, 4, 1), 256, 0, stream>>>(q_all, Wob, 512, 8, 512, 4096,
            0L, 0L, 4194304L, EpiAcc{x2});

        sumsq_f32<<<dim3(8, 64), 256, 0, stream>>>(x2, part);
        finalize_inv<<<8, 64, 0, stream>>>(part, inv2);
        rmsnorm2<<<16384, 256, 0, stream>>>(x2, scale, inv2, x3b);

        gemm128<<<dim3(64, 4, 1), 256, 0, stream>>>(x3b, Wffb, 512, 1, 512, 512,
            0L, 0L, 0L, EpiBias16{h1, bff});
        gemm128<<<dim3(64, 8, 1), 256, 0, stream>>>(h1, Wglb, 512, 1, 512, 512,
            0L, 0L, 0L, EpiGL{g, l, bg, bl});
        final_out<<<16384, 256, 0, stream>>>(x2, scale, inv2, g, l, beta, out);
        return;
    }

    // ================= tier B/C: per-head loop (<= 86 MiB) =================
    u16*   xnb  = (u16*)  (ws);                  //  8 MiB
    float* x2   = (float*)(ws + 8388608L);       // 16 MiB
    u16*   qh   = (u16*)  (ws + 25165824L);      //  8 MiB
    u16*   kh   = (u16*)  (ws + 33554432L);      //  8 MiB (contiguous after qh)
    u16*   vhc  = (u16*)  (ws + 41943040L);      //  8 MiB v, then ctx
    u16*   vT   = (u16*)  (ws + 50331648L);      //  8 MiB
    u16*   Whb  = (u16*)  (ws + 58720256L);      //  1.5 MiB
    u16*   Wob  = (u16*)  (ws + 60293120L);      //  4 MiB
    u16*   Wfb  = (u16*)  (ws + 64487424L);      //  0.5 MiB
    u16*   Wgb  = (u16*)  (ws + 65011712L);      //  0.5 MiB
    u16*   Wlb  = (u16*)  (ws + 65536000L);      //  0.5 MiB
    float* cosT = (float*)(ws + 66060288L);      //  1 MiB
    float* sinT = (float*)(ws + 67108864L);      //  1 MiB
    float* part = (float*)(ws + 68157440L);
    float* inv1 = (float*)(ws + 68159488L);
    float* inv2 = (float*)(ws + 68159552L);
    u16*   sc   = (u16*)  (ws + 68159616L);      // 16 MiB (big) / 2 MiB (small)
    u16*   x3b = qh;  u16* h1 = kh;  u16* g = vhc;  u16* l = vT;
    const bool big = ws_size >= 85002240UL;

    sumsq_f32<<<dim3(8, 64), 256, 0, stream>>>(x, part);
    finalize_inv<<<8, 64, 0, stream>>>(part, inv1);
    rmsnorm1f<<<16384, 256, 0, stream>>>(x, scale, inv1, bo, xnb, x2);
    rope_tables<<<1024, 256, 0, stream>>>(cosT, sinT);
    convert_f2b<<<8192, 256, 0, stream>>>(Wo, Wob, 2097152);
    convert_f2b<<<1024, 256, 0, stream>>>(Wff, Wfb, 262144);
    convert_f2b<<<1024, 256, 0, stream>>>(Wg, Wgb, 262144);
    convert_f2b<<<1024, 256, 0, stream>>>(Wl, Wlb, 262144);

    for (int h = 0; h < 8; h++) {
        convert3<<<3072, 256, 0, stream>>>(Wq + (long)h * 262144, Wk + (long)h * 262144,
                                           Wv + (long)h * 262144, Whb);
        gemm128<<<dim3(64, 4, 3), 256, 0, stream>>>(xnb, Whb, 512, 1, 512, 512, 0L, 262144L, 0L,
                                                    EpiBF16{qh, 4194304L, 512});
        rope_apply<<<16384, 256, 0, stream>>>(qh, cosT, sinT);   // q and k only
        transpose_v<<<dim3(32, 16, 8), 256, 0, stream>>>(vhc, vT);
        if (big) {
            gemm128<<<dim3(8, 8, 8), 256, 0, stream>>>(qh, kh, 512, 1, 512, 512, 524288L, 524288L,
                                                       0L, EpiScale{sc, 1048576L, 1024, sscale});
            softmax_rows4<<<2048, 256, 0, stream>>>(sc);
            gemm128<<<dim3(8, 4, 8), 256, 0, stream>>>(sc, vT, 1024, 1, 1024, 1024, 1048576L,
                                                       524288L, 0L, EpiBF16{vhc, 524288L, 512});
        } else {
            for (int b = 0; b < 8; b++) {
                gemm128<<<dim3(8, 8, 1), 256, 0, stream>>>(qh + (long)b * 524288, kh + (long)b * 524288,
                                                           512, 1, 512, 512, 0L, 0L, 0L,
                                                           EpiScale{sc, 0L, 1024, sscale});
                softmax_rows4<<<256, 256, 0, stream>>>(sc);
                gemm128<<<dim3(8, 4, 1), 256, 0, stream>>>(sc, vT + (long)b * 524288, 1024, 1, 1024,
                                                           1024, 0L, 0L, 0L,
                                                           EpiBF16{vhc + (long)b * 524288, 0L, 512});
            }
        }
        gemm128<<<dim3(64, 4, 1), 256, 0, stream>>>(vhc, Wob + (long)h * 512, 512, 1, 512, 4096,
                                                    0L, 0L, 0L, EpiAcc{x2});
    }

    sumsq_f32<<<dim3(8, 64), 256, 0, stream>>>(x2, part);
    finalize_inv<<<8, 64, 0, stream>>>(part, inv2);
    rmsnorm2<<<16384, 256, 0, stream>>>(x2, scale, inv2, x3b);
    gemm128<<<dim3(64, 4, 1), 256, 0, stream>>>(x3b, Wfb, 512, 1, 512, 512, 0L, 0L, 0L,
                                                EpiBias16{h1, bff});
    gemm128<<<dim3(64, 4, 1), 256, 0, stream>>>(h1, Wgb, 512, 1, 512, 512, 0L, 0L, 0L,
                                                EpiBias16{g, bg});
    gemm128<<<dim3(64, 4, 1), 256, 0, stream>>>(h1, Wlb, 512, 1, 512, 512, 0L, 0L, 0L,
                                                EpiBias16{l, bl});
    final_out<<<16384, 256, 0, stream>>>(x2, scale, inv2, g, l, beta, out);
}